// Round 1
// baseline (1303.842 us; speedup 1.0000x reference)
//
#include <hip/hip_runtime.h>
#include <hip/hip_bf16.h>

namespace {

constexpr int kB = 1024;      // batch
constexpr int kNU = 1024;     // num users
constexpr int kNB = 2048;     // num businesses
constexpr int kNN = 3072;     // total nodes
constexpr int kE = 16384;     // raw edges
constexpr int kET = kE + kNN; // edges + self loops = 19456
constexpr int kH = 768;
constexpr int kHeads = 8;

__device__ __forceinline__ float tof(float x) { return x; }
__device__ __forceinline__ float tof(__hip_bfloat16 x) { return __bfloat162float(x); }
__device__ __forceinline__ void stor(float* p, float v) { *p = v; }
__device__ __forceinline__ void stor(__hip_bfloat16* p, float v) { *p = __float2bfloat16(v); }

// ---------------- generic fp32 tiled GEMM: C = act(A @ B + bias) ----------------
// A: [M,K] row-major (TA = float or bf16), B: [K,N] row-major f32, C: [M,N] (TC)
// M,N multiples of 64; K multiple of 16.
template <typename TA, typename TC>
__global__ __launch_bounds__(256) void gemm_kernel(
    const TA* __restrict__ A, const float* __restrict__ B,
    const float* __restrict__ bias, TC* __restrict__ C,
    int M, int N, int K, int act) {
  __shared__ float As[16][68];
  __shared__ float Bs[16][68];
  const int bm = blockIdx.y * 64;
  const int bn = blockIdx.x * 64;
  const int t = threadIdx.x;
  const int ty = t >> 4, tx = t & 15;
  const int ar = t >> 2, ak = (t & 3) << 2;   // A tile: 64 rows x 16 k
  const int bk = t >> 4, bc = (t & 15) << 2;  // B tile: 16 k x 64 cols
  float acc[4][4] = {};
  for (int k0 = 0; k0 < K; k0 += 16) {
    const TA* ap = A + (size_t)(bm + ar) * K + (k0 + ak);
    float a0 = tof(ap[0]), a1 = tof(ap[1]), a2 = tof(ap[2]), a3 = tof(ap[3]);
    const float* bp = B + (size_t)(k0 + bk) * N + (bn + bc);
    float b0 = bp[0], b1 = bp[1], b2 = bp[2], b3 = bp[3];
    __syncthreads();
    As[ak + 0][ar] = a0; As[ak + 1][ar] = a1; As[ak + 2][ar] = a2; As[ak + 3][ar] = a3;
    Bs[bk][bc + 0] = b0; Bs[bk][bc + 1] = b1; Bs[bk][bc + 2] = b2; Bs[bk][bc + 3] = b3;
    __syncthreads();
#pragma unroll
    for (int kk = 0; kk < 16; ++kk) {
      float av[4], bv[4];
#pragma unroll
      for (int i = 0; i < 4; ++i) av[i] = As[kk][ty * 4 + i];
#pragma unroll
      for (int j = 0; j < 4; ++j) bv[j] = Bs[kk][tx * 4 + j];
#pragma unroll
      for (int i = 0; i < 4; ++i)
#pragma unroll
        for (int j = 0; j < 4; ++j) acc[i][j] = fmaf(av[i], bv[j], acc[i][j]);
    }
  }
#pragma unroll
  for (int i = 0; i < 4; ++i) {
    int r = bm + ty * 4 + i;
#pragma unroll
    for (int j = 0; j < 4; ++j) {
      int c = bn + tx * 4 + j;
      float v = acc[i][j];
      if (bias) v += bias[c];
      if (act) v = fmaxf(v, 0.f);
      stor(&C[(size_t)r * N + c], v);
    }
  }
}

// ---------------- small elementwise / build kernels ----------------
__global__ void img_mean_kernel(const float* __restrict__ img_cls, float* __restrict__ img_mean) {
  int idx = blockIdx.x * 256 + threadIdx.x;
  if (idx >= kB * kH) return;
  int b = idx / kH, c = idx - b * kH;
  const float* p = img_cls + (size_t)b * 3 * kH + c;
  img_mean[idx] = (p[0] + p[kH] + p[2 * kH]) * (1.f / 3.f);
}

__global__ void winner_kernel(const int* __restrict__ business_idx, int* __restrict__ winner) {
  int i = blockIdx.x * 256 + threadIdx.x;
  if (i >= kB) return;
  atomicMax(&winner[business_idx[i] - kNU], i);  // numpy last-occurrence-wins
}

__global__ void build_user_kernel(const int* __restrict__ user_idx,
                                  const float* __restrict__ user_table,
                                  float* __restrict__ x) {
  int i = blockIdx.x;
  int node = user_idx[i];
  for (int c = threadIdx.x; c < kH; c += blockDim.x)
    x[(size_t)node * kH + c] = user_table[(size_t)node * kH + c];
}

__global__ void build_biz_kernel(const int* __restrict__ winner,
                                 const float* __restrict__ text_emb,
                                 const float* __restrict__ img_emb,
                                 const float* __restrict__ biz_feats,
                                 const float* __restrict__ W_bf,
                                 const float* __restrict__ b_bf,
                                 const float* __restrict__ biz_table,
                                 float* __restrict__ x) {
  int m = blockIdx.x;  // business slot 0..2047
  int w = winner[m];
  if (w < 0) return;
  int node = kNU + m;
  float f0 = biz_feats[w * 3], f1 = biz_feats[w * 3 + 1], f2 = biz_feats[w * 3 + 2];
  for (int c = threadIdx.x; c < kH; c += blockDim.x) {
    float meta = f0 * W_bf[c] + f1 * W_bf[kH + c] + f2 * W_bf[2 * kH + c] + b_bf[c];
    float v = (text_emb[(size_t)w * kH + c] + img_emb[(size_t)w * kH + c] + meta +
               biz_table[(size_t)m * kH + c]) * 0.25f;
    x[(size_t)node * kH + c] = v;
  }
}

// ---------------- CSR build (edges grouped by dst) ----------------
__global__ void deg_kernel(const int* __restrict__ ei, int* __restrict__ deg) {
  int e = blockIdx.x * 256 + threadIdx.x;
  if (e >= kET) return;
  int dst = (e < kE) ? ei[kE + e] : (e - kE);
  atomicAdd(&deg[dst], 1);
}

__global__ __launch_bounds__(1024) void scan_kernel(const int* __restrict__ deg,
                                                    int* __restrict__ rowptr,
                                                    int* __restrict__ cursor) {
  __shared__ int sums[1024];
  int t = threadIdx.x;
  int v0 = deg[t * 3], v1 = deg[t * 3 + 1], v2 = deg[t * 3 + 2];
  int s = v0 + v1 + v2;
  sums[t] = s;
  __syncthreads();
  for (int o = 1; o < 1024; o <<= 1) {
    int xv = (t >= o) ? sums[t - o] : 0;
    __syncthreads();
    sums[t] += xv;
    __syncthreads();
  }
  int excl = sums[t] - s;
  rowptr[t * 3] = excl;          cursor[t * 3] = excl;
  rowptr[t * 3 + 1] = excl + v0; cursor[t * 3 + 1] = excl + v0;
  rowptr[t * 3 + 2] = excl + v0 + v1; cursor[t * 3 + 2] = excl + v0 + v1;
  if (t == 1023) rowptr[kNN] = excl + s;
}

__global__ void fill_kernel(const int* __restrict__ ei, int* __restrict__ cursor,
                            int* __restrict__ cols) {
  int e = blockIdx.x * 256 + threadIdx.x;
  if (e >= kET) return;
  int src, dst;
  if (e < kE) { src = ei[e]; dst = ei[kE + e]; } else { src = dst = e - kE; }
  int pos = atomicAdd(&cursor[dst], 1);
  cols[pos] = src;
}

// ---------------- attention scores: s = sum(h * att, -1) ----------------
__global__ __launch_bounds__(256) void scores_kernel(
    const __hip_bfloat16* __restrict__ h, const float* __restrict__ att_src,
    const float* __restrict__ att_dst, float* __restrict__ s_src,
    float* __restrict__ s_dst, int total, int heads) {
  int gw = (blockIdx.x * 256 + threadIdx.x) >> 6;
  int lane = threadIdx.x & 63;
  if (gw >= total) return;
  int hd = gw % heads;
  const __hip_bfloat16* hp = h + (size_t)gw * kH;
  const float* as = att_src + (size_t)hd * kH;
  const float* ad = att_dst + (size_t)hd * kH;
  float ss = 0.f, sd = 0.f;
  for (int c = lane; c < kH; c += 64) {
    float v = tof(hp[c]);
    ss = fmaf(v, as[c], ss);
    sd = fmaf(v, ad[c], sd);
  }
#pragma unroll
  for (int o = 32; o; o >>= 1) { ss += __shfl_down(ss, o); sd += __shfl_down(sd, o); }
  if (lane == 0) { s_src[gw] = ss; s_dst[gw] = sd; }
}

// ---------------- GAT segment softmax + aggregation (one block per node,head) ----
__global__ __launch_bounds__(256) void gat_agg_kernel(
    const int* __restrict__ rowptr, const int* __restrict__ cols,
    const float* __restrict__ s_src, const float* __restrict__ s_dst,
    const __hip_bfloat16* __restrict__ h, const float* __restrict__ bias,
    int heads, int act, __hip_bfloat16* __restrict__ out_bf, float* __restrict__ out_f) {
  __shared__ float red[4];
  const int bid = blockIdx.x;
  const int n = bid / heads;
  const int hd = bid - n * heads;
  const int beg = rowptr[n], end = rowptr[n + 1];
  const float sd = s_dst[(size_t)n * heads + hd];
  const int t = threadIdx.x;

  // pass 1: segment max
  float m = -3.402823466e38f;
  for (int i = beg + t; i < end; i += 256) {
    float e = s_src[(size_t)cols[i] * heads + hd] + sd;
    e = (e > 0.f) ? e : 0.2f * e;
    m = fmaxf(m, e);
  }
#pragma unroll
  for (int o = 32; o; o >>= 1) m = fmaxf(m, __shfl_down(m, o));
  if ((t & 63) == 0) red[t >> 6] = m;
  __syncthreads();
  m = fmaxf(fmaxf(red[0], red[1]), fmaxf(red[2], red[3]));
  __syncthreads();

  // pass 2: denom
  float dsum = 0.f;
  for (int i = beg + t; i < end; i += 256) {
    float e = s_src[(size_t)cols[i] * heads + hd] + sd;
    e = (e > 0.f) ? e : 0.2f * e;
    dsum += expf(e - m);
  }
#pragma unroll
  for (int o = 32; o; o >>= 1) dsum += __shfl_down(dsum, o);
  if ((t & 63) == 0) red[t >> 6] = dsum;
  __syncthreads();
  dsum = red[0] + red[1] + red[2] + red[3] + 1e-16f;

  // pass 3: weighted aggregation; each thread owns channels t, t+256, t+512
  float acc0 = 0.f, acc1 = 0.f, acc2 = 0.f;
  const size_t hs = (size_t)heads * kH;
  for (int i = beg; i < end; ++i) {
    int src = cols[i];
    float e = s_src[(size_t)src * heads + hd] + sd;
    e = (e > 0.f) ? e : 0.2f * e;
    float w = expf(e - m) / dsum;
    const __hip_bfloat16* hp = h + (size_t)src * hs + (size_t)hd * kH;
    acc0 = fmaf(w, tof(hp[t]), acc0);
    acc1 = fmaf(w, tof(hp[t + 256]), acc1);
    acc2 = fmaf(w, tof(hp[t + 512]), acc2);
  }
  const int cbase = hd * kH;
  float v0 = acc0 + bias[cbase + t];
  float v1 = acc1 + bias[cbase + t + 256];
  float v2 = acc2 + bias[cbase + t + 512];
  if (act) { v0 = fmaxf(v0, 0.f); v1 = fmaxf(v1, 0.f); v2 = fmaxf(v2, 0.f); }
  size_t ob = (size_t)n * hs + cbase;
  if (out_bf) {
    out_bf[ob + t] = __float2bfloat16(v0);
    out_bf[ob + t + 256] = __float2bfloat16(v1);
    out_bf[ob + t + 512] = __float2bfloat16(v2);
  } else {
    out_f[ob + t] = v0;
    out_f[ob + t + 256] = v1;
    out_f[ob + t + 512] = v2;
  }
}

// ---------------- MLP head ----------------
__global__ void cat_kernel(const float* __restrict__ xf, const float* __restrict__ text_emb,
                           const float* __restrict__ img_emb, const int* __restrict__ user_idx,
                           const int* __restrict__ business_idx, float* __restrict__ cat) {
  int b = blockIdx.x;
  int u = user_idx[b], z = business_idx[b];
  float* crow = cat + (size_t)b * 4 * kH;
  for (int c = threadIdx.x; c < kH; c += blockDim.x) {
    crow[c] = xf[(size_t)u * kH + c];
    crow[kH + c] = xf[(size_t)z * kH + c];
    crow[2 * kH + c] = text_emb[(size_t)b * kH + c];
    crow[3 * kH + c] = img_emb[(size_t)b * kH + c];
  }
}

__global__ __launch_bounds__(256) void final_kernel(const float* __restrict__ m2,
                                                    const float* __restrict__ Wf3,
                                                    const float* __restrict__ bf3,
                                                    float* __restrict__ out) {
  int b = (blockIdx.x * 256 + threadIdx.x) >> 6;
  int lane = threadIdx.x & 63;
  if (b >= kB) return;
  float s = 0.f;
  for (int c = lane; c < kH; c += 64) s = fmaf(m2[(size_t)b * kH + c], Wf3[c], s);
#pragma unroll
  for (int o = 32; o; o >>= 1) s += __shfl_down(s, o);
  if (lane == 0) out[b] = s + bf3[0];
}

}  // namespace

extern "C" void kernel_launch(void* const* d_in, const int* in_sizes, int n_in,
                              void* d_out, int out_size, void* d_ws, size_t ws_size,
                              hipStream_t stream) {
  const float* text_cls = (const float*)d_in[0];
  const float* img_cls = (const float*)d_in[1];
  const float* biz_feats = (const float*)d_in[2];
  const float* W_text = (const float*)d_in[3];
  const float* b_text = (const float*)d_in[4];
  const float* W_img = (const float*)d_in[5];
  const float* b_img = (const float*)d_in[6];
  const float* W_bf = (const float*)d_in[7];
  const float* b_bf = (const float*)d_in[8];
  const float* user_table = (const float*)d_in[9];
  const float* biz_table = (const float*)d_in[10];
  const float* W1 = (const float*)d_in[11];
  const float* att_src1 = (const float*)d_in[12];
  const float* att_dst1 = (const float*)d_in[13];
  const float* b1 = (const float*)d_in[14];
  const float* W2 = (const float*)d_in[15];
  const float* att_src2 = (const float*)d_in[16];
  const float* att_dst2 = (const float*)d_in[17];
  const float* b2 = (const float*)d_in[18];
  const float* Wf1 = (const float*)d_in[19];
  const float* bf1 = (const float*)d_in[20];
  const float* Wf2 = (const float*)d_in[21];
  const float* bf2 = (const float*)d_in[22];
  const float* Wf3 = (const float*)d_in[23];
  const float* bf3 = (const float*)d_in[24];
  const int* user_idx = (const int*)d_in[25];
  const int* business_idx = (const int*)d_in[26];
  const int* edge_index = (const int*)d_in[27];
  float* out = (float*)d_out;
  (void)in_sizes; (void)n_in; (void)out_size; (void)ws_size;

  char* base = (char*)d_ws;
  size_t off = 0;
  auto alloc = [&](size_t bytes) -> void* {
    void* p = base + off;
    off = (off + bytes + 255) & ~(size_t)255;
    return p;
  };
  float* x = (float*)alloc((size_t)kNN * kH * 4);
  float* text_emb = (float*)alloc((size_t)kB * kH * 4);
  float* img_emb = (float*)alloc((size_t)kB * kH * 4);
  float* img_mean = (float*)alloc((size_t)kB * kH * 4);
  __hip_bfloat16* h1 = (__hip_bfloat16*)alloc((size_t)kNN * kHeads * kH * 2);
  __hip_bfloat16* x2 = (__hip_bfloat16*)alloc((size_t)kNN * kHeads * kH * 2);
  __hip_bfloat16* h2 = (__hip_bfloat16*)alloc((size_t)kNN * kH * 2);
  float* xf = (float*)alloc((size_t)kNN * kH * 4);
  float* s1s = (float*)alloc((size_t)kNN * kHeads * 4);
  float* s1d = (float*)alloc((size_t)kNN * kHeads * 4);
  float* s2s = (float*)alloc((size_t)kNN * 4);
  float* s2d = (float*)alloc((size_t)kNN * 4);
  float* catb = (float*)alloc((size_t)kB * 4 * kH * 4);
  float* m1 = (float*)alloc((size_t)kB * 2 * kH * 4);
  float* m2 = (float*)alloc((size_t)kB * kH * 4);
  int* deg = (int*)alloc((size_t)kNN * 4);
  int* rowptr = (int*)alloc((size_t)(kNN + 1) * 4);
  int* cursor = (int*)alloc((size_t)kNN * 4);
  int* cols = (int*)alloc((size_t)kET * 4);
  int* winner = (int*)alloc((size_t)kNB * 4);

  hipMemsetAsync(x, 0, (size_t)kNN * kH * 4, stream);
  hipMemsetAsync(deg, 0, (size_t)kNN * 4, stream);
  hipMemsetAsync(winner, 0xFF, (size_t)kNB * 4, stream);

  // encoders
  img_mean_kernel<<<(kB * kH + 255) / 256, 256, 0, stream>>>(img_cls, img_mean);
  dim3 g1(kH / 64, kB / 64);
  gemm_kernel<float, float><<<g1, 256, 0, stream>>>(text_cls, W_text, b_text, text_emb, kB, kH, kH, 0);
  gemm_kernel<float, float><<<g1, 256, 0, stream>>>(img_mean, W_img, b_img, img_emb, kB, kH, kH, 0);

  // build node features
  winner_kernel<<<(kB + 255) / 256, 256, 0, stream>>>(business_idx, winner);
  build_user_kernel<<<kB, 256, 0, stream>>>(user_idx, user_table, x);
  build_biz_kernel<<<kNB, 256, 0, stream>>>(winner, text_emb, img_emb, biz_feats, W_bf, b_bf,
                                            biz_table, x);

  // CSR (edges + self loops, grouped by dst)
  deg_kernel<<<(kET + 255) / 256, 256, 0, stream>>>(edge_index, deg);
  scan_kernel<<<1, 1024, 0, stream>>>(deg, rowptr, cursor);
  fill_kernel<<<(kET + 255) / 256, 256, 0, stream>>>(edge_index, cursor, cols);

  // GAT layer 1 (8 heads, C=768)
  dim3 g3(kHeads * kH / 64, kNN / 64);
  gemm_kernel<float, __hip_bfloat16><<<g3, 256, 0, stream>>>(x, W1, nullptr, h1, kNN, kHeads * kH, kH, 0);
  scores_kernel<<<(kNN * kHeads + 3) / 4, 256, 0, stream>>>(h1, att_src1, att_dst1, s1s, s1d,
                                                            kNN * kHeads, kHeads);
  gat_agg_kernel<<<kNN * kHeads, 256, 0, stream>>>(rowptr, cols, s1s, s1d, h1, b1, kHeads, 1,
                                                   x2, nullptr);

  // GAT layer 2 (1 head)
  dim3 g4(kH / 64, kNN / 64);
  gemm_kernel<__hip_bfloat16, __hip_bfloat16><<<g4, 256, 0, stream>>>(x2, W2, nullptr, h2, kNN, kH,
                                                                      kHeads * kH, 0);
  scores_kernel<<<(kNN + 3) / 4, 256, 0, stream>>>(h2, att_src2, att_dst2, s2s, s2d, kNN, 1);
  gat_agg_kernel<<<kNN, 256, 0, stream>>>(rowptr, cols, s2s, s2d, h2, b2, 1, 0, nullptr, xf);

  // MLP head
  cat_kernel<<<kB, 256, 0, stream>>>(xf, text_emb, img_emb, user_idx, business_idx, catb);
  dim3 g5(2 * kH / 64, kB / 64);
  gemm_kernel<float, float><<<g5, 256, 0, stream>>>(catb, Wf1, bf1, m1, kB, 2 * kH, 4 * kH, 1);
  dim3 g6(kH / 64, kB / 64);
  gemm_kernel<float, float><<<g6, 256, 0, stream>>>(m1, Wf2, bf2, m2, kB, kH, 2 * kH, 1);
  final_kernel<<<(kB * 64 + 255) / 256, 256, 0, stream>>>(m2, Wf3, bf3, out);
}

// Round 2
// 421.464 us; speedup vs baseline: 3.0936x; 3.0936x over previous
//
#include <hip/hip_runtime.h>
#include <hip/hip_bf16.h>

namespace {

constexpr int kB = 1024;      // batch
constexpr int kNU = 1024;     // num users
constexpr int kNB = 2048;     // num businesses
constexpr int kNN = 3072;     // total nodes
constexpr int kE = 16384;     // raw edges
constexpr int kET = kE + kNN; // edges + self loops = 19456
constexpr int kH = 768;
constexpr int kHeads = 8;

typedef __attribute__((ext_vector_type(8))) short bf16x8_t;
typedef __attribute__((ext_vector_type(4))) float f32x4_t;

__device__ __forceinline__ float tof(float x) { return x; }
__device__ __forceinline__ float tof(__hip_bfloat16 x) { return __bfloat162float(x); }
__device__ __forceinline__ void stor(float* p, float v) { *p = v; }
__device__ __forceinline__ void stor(__hip_bfloat16* p, float v) { *p = __float2bfloat16(v); }

__device__ __forceinline__ void gload_lds16(const void* g, void* l) {
  __builtin_amdgcn_global_load_lds(
      (const __attribute__((address_space(1))) void*)g,
      (__attribute__((address_space(3))) void*)l, 16, 0, 0);
}

// ---------------- bf16 MFMA GEMM: C = act(A @ B + bias) ----------------
// A: [M,K] bf16 row-major; Bt: [N,K] bf16 row-major (B transposed).
// 4 waves in 2x2; each wave owns (FM*16)x(FN*16); BM=2*FM*16, BN=2*FN*16.
// BK=32 (one MFMA k-slice), double-buffered LDS, prefetch-next-before-compute.
template <int BM, int BN, int FM, int FN, typename TC>
__global__ __launch_bounds__(256) void mfma_gemm(
    const __hip_bfloat16* __restrict__ A, const __hip_bfloat16* __restrict__ Bt,
    const float* __restrict__ bias, TC* __restrict__ C,
    int M, int N, int K, int act) {
  __shared__ __align__(16) __hip_bfloat16 As[2][BM][32];
  __shared__ __align__(16) __hip_bfloat16 Bs[2][BN][32];
  const int t = threadIdx.x;
  const int w = t >> 6, lane = t & 63;
  const int wm = w >> 1, wn = w & 1;
  const int bm = blockIdx.y * BM, bn = blockIdx.x * BN;
  const int lr = lane & 15, lg = lane >> 4;

  f32x4_t acc[FM][FN];
#pragma unroll
  for (int m = 0; m < FM; ++m)
#pragma unroll
    for (int n = 0; n < FN; ++n) acc[m][n] = (f32x4_t){0.f, 0.f, 0.f, 0.f};

  auto stage = [&](int buf, int kt) {
    const int k0 = kt << 5;
#pragma unroll
    for (int i = 0; i < BM / 64; ++i) {
      int L = i * 256 + t;
      gload_lds16(A + (size_t)(bm + (L >> 2)) * K + k0 + (L & 3) * 8,
                  (char*)(&As[buf][0][0]) + ((size_t)(i * 256 + w * 64)) * 16);
    }
#pragma unroll
    for (int i = 0; i < BN / 64; ++i) {
      int L = i * 256 + t;
      gload_lds16(Bt + (size_t)(bn + (L >> 2)) * K + k0 + (L & 3) * 8,
                  (char*)(&Bs[buf][0][0]) + ((size_t)(i * 256 + w * 64)) * 16);
    }
  };

  const int NT = K >> 5;
  stage(0, 0);
  __syncthreads();
  for (int kt = 0; kt < NT; ++kt) {
    const int cur = kt & 1;
    if (kt + 1 < NT) stage(cur ^ 1, kt + 1);
    bf16x8_t af[FM], bv[FN];
#pragma unroll
    for (int m = 0; m < FM; ++m)
      af[m] = *(const bf16x8_t*)&As[cur][wm * FM * 16 + m * 16 + lr][lg * 8];
#pragma unroll
    for (int n = 0; n < FN; ++n)
      bv[n] = *(const bf16x8_t*)&Bs[cur][wn * FN * 16 + n * 16 + lr][lg * 8];
#pragma unroll
    for (int m = 0; m < FM; ++m)
#pragma unroll
      for (int n = 0; n < FN; ++n)
        acc[m][n] = __builtin_amdgcn_mfma_f32_16x16x32_bf16(af[m], bv[n], acc[m][n], 0, 0, 0);
    __syncthreads();  // drains prefetch (vmcnt) + protects buffer reuse
  }

#pragma unroll
  for (int m = 0; m < FM; ++m) {
    const int row0 = bm + wm * FM * 16 + m * 16 + lg * 4;
#pragma unroll
    for (int n = 0; n < FN; ++n) {
      const int cn = bn + wn * FN * 16 + n * 16 + lr;
      const float bvv = bias ? bias[cn] : 0.f;
#pragma unroll
      for (int r = 0; r < 4; ++r) {
        float v = acc[m][n][r] + bvv;
        if (act) v = fmaxf(v, 0.f);
        stor(&C[(size_t)(row0 + r) * N + cn], v);
      }
    }
  }
}

// ---------------- transpose+convert: in f32 [K][N] -> out bf16 [N][K] ----------------
__global__ __launch_bounds__(256) void transp_kernel(const float* __restrict__ in,
                                                     __hip_bfloat16* __restrict__ out,
                                                     int K, int N) {
  __shared__ float tl[32][33];
  const int n0 = blockIdx.x * 32, k0 = blockIdx.y * 32;
  const int t = threadIdx.x;
  const int r = t >> 3, c = (t & 7) * 4;
#pragma unroll
  for (int i = 0; i < 4; ++i) tl[r][c + i] = in[(size_t)(k0 + r) * N + n0 + c + i];
  __syncthreads();
  __hip_bfloat16* op = out + (size_t)(n0 + r) * K + k0 + c;
#pragma unroll
  for (int i = 0; i < 4; ++i) op[i] = __float2bfloat16(tl[c + i][r]);
}

// ---------------- f32 -> bf16 convert (4 elems/thread) ----------------
__global__ void f2b_kernel(const float* __restrict__ in, __hip_bfloat16* __restrict__ out, int n4) {
  int i = blockIdx.x * 256 + threadIdx.x;
  if (i >= n4) return;
  float4 v = ((const float4*)in)[i];
  __hip_bfloat16* o = out + (size_t)i * 4;
  o[0] = __float2bfloat16(v.x); o[1] = __float2bfloat16(v.y);
  o[2] = __float2bfloat16(v.z); o[3] = __float2bfloat16(v.w);
}

// ---------------- small elementwise / build kernels ----------------
__global__ void img_mean_kernel(const float* __restrict__ img_cls,
                                __hip_bfloat16* __restrict__ img_mean_bf) {
  int idx = blockIdx.x * 256 + threadIdx.x;
  if (idx >= kB * kH) return;
  int b = idx / kH, c = idx - b * kH;
  const float* p = img_cls + (size_t)b * 3 * kH + c;
  img_mean_bf[idx] = __float2bfloat16((p[0] + p[kH] + p[2 * kH]) * (1.f / 3.f));
}

__global__ void winner_kernel(const int* __restrict__ business_idx, int* __restrict__ winner) {
  int i = blockIdx.x * 256 + threadIdx.x;
  if (i >= kB) return;
  atomicMax(&winner[business_idx[i] - kNU], i);  // numpy last-occurrence-wins
}

__global__ void build_user_kernel(const int* __restrict__ user_idx,
                                  const float* __restrict__ user_table,
                                  __hip_bfloat16* __restrict__ xb) {
  int i = blockIdx.x;
  int node = user_idx[i];
  for (int c = threadIdx.x; c < kH; c += blockDim.x)
    xb[(size_t)node * kH + c] = __float2bfloat16(user_table[(size_t)node * kH + c]);
}

__global__ void build_biz_kernel(const int* __restrict__ winner,
                                 const float* __restrict__ text_emb,
                                 const float* __restrict__ img_emb,
                                 const float* __restrict__ biz_feats,
                                 const float* __restrict__ W_bf,
                                 const float* __restrict__ b_bf,
                                 const float* __restrict__ biz_table,
                                 __hip_bfloat16* __restrict__ xb) {
  int m = blockIdx.x;
  int w = winner[m];
  if (w < 0) return;
  int node = kNU + m;
  float f0 = biz_feats[w * 3], f1 = biz_feats[w * 3 + 1], f2 = biz_feats[w * 3 + 2];
  for (int c = threadIdx.x; c < kH; c += blockDim.x) {
    float meta = f0 * W_bf[c] + f1 * W_bf[kH + c] + f2 * W_bf[2 * kH + c] + b_bf[c];
    float v = (text_emb[(size_t)w * kH + c] + img_emb[(size_t)w * kH + c] + meta +
               biz_table[(size_t)m * kH + c]) * 0.25f;
    xb[(size_t)node * kH + c] = __float2bfloat16(v);
  }
}

// ---------------- CSR build (edges grouped by dst) ----------------
__global__ void deg_kernel(const int* __restrict__ ei, int* __restrict__ deg) {
  int e = blockIdx.x * 256 + threadIdx.x;
  if (e >= kET) return;
  int dst = (e < kE) ? ei[kE + e] : (e - kE);
  atomicAdd(&deg[dst], 1);
}

__global__ __launch_bounds__(1024) void scan_kernel(const int* __restrict__ deg,
                                                    int* __restrict__ rowptr,
                                                    int* __restrict__ cursor) {
  __shared__ int sums[1024];
  int t = threadIdx.x;
  int v0 = deg[t * 3], v1 = deg[t * 3 + 1], v2 = deg[t * 3 + 2];
  int s = v0 + v1 + v2;
  sums[t] = s;
  __syncthreads();
  for (int o = 1; o < 1024; o <<= 1) {
    int xv = (t >= o) ? sums[t - o] : 0;
    __syncthreads();
    sums[t] += xv;
    __syncthreads();
  }
  int excl = sums[t] - s;
  rowptr[t * 3] = excl;          cursor[t * 3] = excl;
  rowptr[t * 3 + 1] = excl + v0; cursor[t * 3 + 1] = excl + v0;
  rowptr[t * 3 + 2] = excl + v0 + v1; cursor[t * 3 + 2] = excl + v0 + v1;
  if (t == 1023) rowptr[kNN] = excl + s;
}

__global__ void fill_kernel(const int* __restrict__ ei, int* __restrict__ cursor,
                            int* __restrict__ cols) {
  int e = blockIdx.x * 256 + threadIdx.x;
  if (e >= kET) return;
  int src, dst;
  if (e < kE) { src = ei[e]; dst = ei[kE + e]; } else { src = dst = e - kE; }
  int pos = atomicAdd(&cursor[dst], 1);
  cols[pos] = src;
}

// ---------------- attention scores: s = sum(h * att, -1) ----------------
__global__ __launch_bounds__(256) void scores_kernel(
    const __hip_bfloat16* __restrict__ h, const float* __restrict__ att_src,
    const float* __restrict__ att_dst, float* __restrict__ s_src,
    float* __restrict__ s_dst, int total, int heads) {
  int gw = (blockIdx.x * 256 + threadIdx.x) >> 6;
  int lane = threadIdx.x & 63;
  if (gw >= total) return;
  int hd = gw % heads;
  const __hip_bfloat16* hp = h + (size_t)gw * kH;
  const float* as = att_src + (size_t)hd * kH;
  const float* ad = att_dst + (size_t)hd * kH;
  float ss = 0.f, sd = 0.f;
  for (int c = lane; c < kH; c += 64) {
    float v = tof(hp[c]);
    ss = fmaf(v, as[c], ss);
    sd = fmaf(v, ad[c], sd);
  }
#pragma unroll
  for (int o = 32; o; o >>= 1) { ss += __shfl_down(ss, o); sd += __shfl_down(sd, o); }
  if (lane == 0) { s_src[gw] = ss; s_dst[gw] = sd; }
}

// ---------------- GAT segment softmax + aggregation (one block per node,head) ----
__global__ __launch_bounds__(256) void gat_agg_kernel(
    const int* __restrict__ rowptr, const int* __restrict__ cols,
    const float* __restrict__ s_src, const float* __restrict__ s_dst,
    const __hip_bfloat16* __restrict__ h, const float* __restrict__ bias,
    int heads, int act, __hip_bfloat16* __restrict__ out_bf, float* __restrict__ out_f) {
  __shared__ float red[4];
  const int bid = blockIdx.x;
  const int n = bid / heads;
  const int hd = bid - n * heads;
  const int beg = rowptr[n], end = rowptr[n + 1];
  const float sd = s_dst[(size_t)n * heads + hd];
  const int t = threadIdx.x;

  float m = -3.402823466e38f;
  for (int i = beg + t; i < end; i += 256) {
    float e = s_src[(size_t)cols[i] * heads + hd] + sd;
    e = (e > 0.f) ? e : 0.2f * e;
    m = fmaxf(m, e);
  }
#pragma unroll
  for (int o = 32; o; o >>= 1) m = fmaxf(m, __shfl_down(m, o));
  if ((t & 63) == 0) red[t >> 6] = m;
  __syncthreads();
  m = fmaxf(fmaxf(red[0], red[1]), fmaxf(red[2], red[3]));
  __syncthreads();

  float dsum = 0.f;
  for (int i = beg + t; i < end; i += 256) {
    float e = s_src[(size_t)cols[i] * heads + hd] + sd;
    e = (e > 0.f) ? e : 0.2f * e;
    dsum += expf(e - m);
  }
#pragma unroll
  for (int o = 32; o; o >>= 1) dsum += __shfl_down(dsum, o);
  if ((t & 63) == 0) red[t >> 6] = dsum;
  __syncthreads();
  dsum = red[0] + red[1] + red[2] + red[3] + 1e-16f;

  float acc0 = 0.f, acc1 = 0.f, acc2 = 0.f;
  const size_t hs = (size_t)heads * kH;
  for (int i = beg; i < end; ++i) {
    int src = cols[i];
    float e = s_src[(size_t)src * heads + hd] + sd;
    e = (e > 0.f) ? e : 0.2f * e;
    float w = expf(e - m) / dsum;
    const __hip_bfloat16* hp = h + (size_t)src * hs + (size_t)hd * kH;
    acc0 = fmaf(w, tof(hp[t]), acc0);
    acc1 = fmaf(w, tof(hp[t + 256]), acc1);
    acc2 = fmaf(w, tof(hp[t + 512]), acc2);
  }
  const int cbase = hd * kH;
  float v0 = acc0 + bias[cbase + t];
  float v1 = acc1 + bias[cbase + t + 256];
  float v2 = acc2 + bias[cbase + t + 512];
  if (act) { v0 = fmaxf(v0, 0.f); v1 = fmaxf(v1, 0.f); v2 = fmaxf(v2, 0.f); }
  size_t ob = (size_t)n * hs + cbase;
  if (out_bf) {
    out_bf[ob + t] = __float2bfloat16(v0);
    out_bf[ob + t + 256] = __float2bfloat16(v1);
    out_bf[ob + t + 512] = __float2bfloat16(v2);
  } else {
    out_f[ob + t] = v0;
    out_f[ob + t + 256] = v1;
    out_f[ob + t + 512] = v2;
  }
}

// ---------------- MLP head ----------------
__global__ void cat_kernel(const float* __restrict__ xf, const float* __restrict__ text_emb,
                           const float* __restrict__ img_emb, const int* __restrict__ user_idx,
                           const int* __restrict__ business_idx, __hip_bfloat16* __restrict__ cat) {
  int b = blockIdx.x;
  int u = user_idx[b], z = business_idx[b];
  __hip_bfloat16* crow = cat + (size_t)b * 4 * kH;
  for (int c = threadIdx.x; c < kH; c += blockDim.x) {
    crow[c] = __float2bfloat16(xf[(size_t)u * kH + c]);
    crow[kH + c] = __float2bfloat16(xf[(size_t)z * kH + c]);
    crow[2 * kH + c] = __float2bfloat16(text_emb[(size_t)b * kH + c]);
    crow[3 * kH + c] = __float2bfloat16(img_emb[(size_t)b * kH + c]);
  }
}

__global__ __launch_bounds__(256) void final_kernel(const float* __restrict__ m2,
                                                    const float* __restrict__ Wf3,
                                                    const float* __restrict__ bf3,
                                                    float* __restrict__ out) {
  int b = (blockIdx.x * 256 + threadIdx.x) >> 6;
  int lane = threadIdx.x & 63;
  if (b >= kB) return;
  float s = 0.f;
  for (int c = lane; c < kH; c += 64) s = fmaf(m2[(size_t)b * kH + c], Wf3[c], s);
#pragma unroll
  for (int o = 32; o; o >>= 1) s += __shfl_down(s, o);
  if (lane == 0) out[b] = s + bf3[0];
}

}  // namespace

extern "C" void kernel_launch(void* const* d_in, const int* in_sizes, int n_in,
                              void* d_out, int out_size, void* d_ws, size_t ws_size,
                              hipStream_t stream) {
  const float* text_cls = (const float*)d_in[0];
  const float* img_cls = (const float*)d_in[1];
  const float* biz_feats = (const float*)d_in[2];
  const float* W_text = (const float*)d_in[3];
  const float* b_text = (const float*)d_in[4];
  const float* W_img = (const float*)d_in[5];
  const float* b_img = (const float*)d_in[6];
  const float* W_bf = (const float*)d_in[7];
  const float* b_bf = (const float*)d_in[8];
  const float* user_table = (const float*)d_in[9];
  const float* biz_table = (const float*)d_in[10];
  const float* W1 = (const float*)d_in[11];
  const float* att_src1 = (const float*)d_in[12];
  const float* att_dst1 = (const float*)d_in[13];
  const float* b1 = (const float*)d_in[14];
  const float* W2 = (const float*)d_in[15];
  const float* att_src2 = (const float*)d_in[16];
  const float* att_dst2 = (const float*)d_in[17];
  const float* b2 = (const float*)d_in[18];
  const float* Wf1 = (const float*)d_in[19];
  const float* bf1 = (const float*)d_in[20];
  const float* Wf2 = (const float*)d_in[21];
  const float* bf2 = (const float*)d_in[22];
  const float* Wf3 = (const float*)d_in[23];
  const float* bf3 = (const float*)d_in[24];
  const int* user_idx = (const int*)d_in[25];
  const int* business_idx = (const int*)d_in[26];
  const int* edge_index = (const int*)d_in[27];
  float* out = (float*)d_out;
  (void)in_sizes; (void)n_in; (void)out_size; (void)ws_size;

  char* base = (char*)d_ws;
  size_t off = 0;
  auto alloc = [&](size_t bytes) -> void* {
    void* p = base + off;
    off = (off + bytes + 255) & ~(size_t)255;
    return p;
  };
  __hip_bfloat16* xb = (__hip_bfloat16*)alloc((size_t)kNN * kH * 2);
  __hip_bfloat16* text_bf = (__hip_bfloat16*)alloc((size_t)kB * kH * 2);
  __hip_bfloat16* imgm_bf = (__hip_bfloat16*)alloc((size_t)kB * kH * 2);
  float* text_emb = (float*)alloc((size_t)kB * kH * 4);
  float* img_emb = (float*)alloc((size_t)kB * kH * 4);
  __hip_bfloat16* Wtt = (__hip_bfloat16*)alloc((size_t)kH * kH * 2);
  __hip_bfloat16* Wit = (__hip_bfloat16*)alloc((size_t)kH * kH * 2);
  __hip_bfloat16* W1t = (__hip_bfloat16*)alloc((size_t)kHeads * kH * kH * 2);
  __hip_bfloat16* W2t = (__hip_bfloat16*)alloc((size_t)kH * kHeads * kH * 2);
  __hip_bfloat16* Wf1t = (__hip_bfloat16*)alloc((size_t)2 * kH * 4 * kH * 2);
  __hip_bfloat16* Wf2t = (__hip_bfloat16*)alloc((size_t)kH * 2 * kH * 2);
  __hip_bfloat16* h1 = (__hip_bfloat16*)alloc((size_t)kNN * kHeads * kH * 2);
  __hip_bfloat16* x2 = (__hip_bfloat16*)alloc((size_t)kNN * kHeads * kH * 2);
  __hip_bfloat16* h2 = (__hip_bfloat16*)alloc((size_t)kNN * kH * 2);
  float* xf = (float*)alloc((size_t)kNN * kH * 4);
  float* s1s = (float*)alloc((size_t)kNN * kHeads * 4);
  float* s1d = (float*)alloc((size_t)kNN * kHeads * 4);
  float* s2s = (float*)alloc((size_t)kNN * 4);
  float* s2d = (float*)alloc((size_t)kNN * 4);
  __hip_bfloat16* catb = (__hip_bfloat16*)alloc((size_t)kB * 4 * kH * 2);
  __hip_bfloat16* m1 = (__hip_bfloat16*)alloc((size_t)kB * 2 * kH * 2);
  float* m2 = (float*)alloc((size_t)kB * kH * 4);
  int* deg = (int*)alloc((size_t)kNN * 4);
  int* rowptr = (int*)alloc((size_t)(kNN + 1) * 4);
  int* cursor = (int*)alloc((size_t)kNN * 4);
  int* cols = (int*)alloc((size_t)kET * 4);
  int* winner = (int*)alloc((size_t)kNB * 4);

  hipMemsetAsync(xb, 0, (size_t)kNN * kH * 2, stream);
  hipMemsetAsync(deg, 0, (size_t)kNN * 4, stream);
  hipMemsetAsync(winner, 0xFF, (size_t)kNB * 4, stream);

  // weight transposes (f32 [K][N] -> bf16 [N][K])
  transp_kernel<<<dim3(kH / 32, kH / 32), 256, 0, stream>>>(W_text, Wtt, kH, kH);
  transp_kernel<<<dim3(kH / 32, kH / 32), 256, 0, stream>>>(W_img, Wit, kH, kH);
  transp_kernel<<<dim3(kHeads * kH / 32, kH / 32), 256, 0, stream>>>(W1, W1t, kH, kHeads * kH);
  transp_kernel<<<dim3(kH / 32, kHeads * kH / 32), 256, 0, stream>>>(W2, W2t, kHeads * kH, kH);
  transp_kernel<<<dim3(2 * kH / 32, 4 * kH / 32), 256, 0, stream>>>(Wf1, Wf1t, 4 * kH, 2 * kH);
  transp_kernel<<<dim3(kH / 32, 2 * kH / 32), 256, 0, stream>>>(Wf2, Wf2t, 2 * kH, kH);

  // input conversions
  f2b_kernel<<<(kB * kH / 4 + 255) / 256, 256, 0, stream>>>(text_cls, text_bf, kB * kH / 4);
  img_mean_kernel<<<(kB * kH + 255) / 256, 256, 0, stream>>>(img_cls, imgm_bf);

  // encoders (bf16 MFMA, f32 out)
  mfma_gemm<64, 64, 2, 2, float><<<dim3(kH / 64, kB / 64), 256, 0, stream>>>(
      text_bf, Wtt, b_text, text_emb, kB, kH, kH, 0);
  mfma_gemm<64, 64, 2, 2, float><<<dim3(kH / 64, kB / 64), 256, 0, stream>>>(
      imgm_bf, Wit, b_img, img_emb, kB, kH, kH, 0);

  // node features
  winner_kernel<<<(kB + 255) / 256, 256, 0, stream>>>(business_idx, winner);
  build_user_kernel<<<kB, 256, 0, stream>>>(user_idx, user_table, xb);
  build_biz_kernel<<<kNB, 256, 0, stream>>>(winner, text_emb, img_emb, biz_feats, W_bf, b_bf,
                                            biz_table, xb);

  // CSR
  deg_kernel<<<(kET + 255) / 256, 256, 0, stream>>>(edge_index, deg);
  scan_kernel<<<1, 1024, 0, stream>>>(deg, rowptr, cursor);
  fill_kernel<<<(kET + 255) / 256, 256, 0, stream>>>(edge_index, cursor, cols);

  // GAT layer 1 (8 heads)
  mfma_gemm<128, 128, 4, 4, __hip_bfloat16><<<dim3(kHeads * kH / 128, kNN / 128), 256, 0, stream>>>(
      xb, W1t, nullptr, h1, kNN, kHeads * kH, kH, 0);
  scores_kernel<<<(kNN * kHeads + 3) / 4, 256, 0, stream>>>(h1, att_src1, att_dst1, s1s, s1d,
                                                            kNN * kHeads, kHeads);
  gat_agg_kernel<<<kNN * kHeads, 256, 0, stream>>>(rowptr, cols, s1s, s1d, h1, b1, kHeads, 1,
                                                   x2, nullptr);

  // GAT layer 2 (1 head)
  mfma_gemm<128, 128, 4, 4, __hip_bfloat16><<<dim3(kH / 128, kNN / 128), 256, 0, stream>>>(
      x2, W2t, nullptr, h2, kNN, kH, kHeads * kH, 0);
  scores_kernel<<<(kNN + 3) / 4, 256, 0, stream>>>(h2, att_src2, att_dst2, s2s, s2d, kNN, 1);
  gat_agg_kernel<<<kNN, 256, 0, stream>>>(rowptr, cols, s2s, s2d, h2, b2, 1, 0, nullptr, xf);

  // MLP head
  cat_kernel<<<kB, 256, 0, stream>>>(xf, text_emb, img_emb, user_idx, business_idx, catb);
  mfma_gemm<64, 64, 2, 2, __hip_bfloat16><<<dim3(2 * kH / 64, kB / 64), 256, 0, stream>>>(
      catb, Wf1t, bf1, m1, kB, 2 * kH, 4 * kH, 1);
  mfma_gemm<64, 64, 2, 2, float><<<dim3(kH / 64, kB / 64), 256, 0, stream>>>(
      m1, Wf2t, bf2, m2, kB, kH, 2 * kH, 1);
  final_kernel<<<(kB * 64 + 255) / 256, 256, 0, stream>>>(m2, Wf3, bf3, out);
}

// Round 3
// 348.693 us; speedup vs baseline: 3.7392x; 1.2087x over previous
//
#include <hip/hip_runtime.h>
#include <hip/hip_bf16.h>

namespace {

constexpr int kB = 1024;      // batch
constexpr int kNU = 1024;     // num users
constexpr int kNB = 2048;     // num businesses
constexpr int kNN = 3072;     // total nodes
constexpr int kE = 16384;     // raw edges
constexpr int kET = kE + kNN; // edges + self loops = 19456
constexpr int kH = 768;
constexpr int kHeads = 8;
constexpr int kSplitK = 4;    // GAT2 split-K factor

typedef __attribute__((ext_vector_type(8))) short bf16x8_t;
typedef __attribute__((ext_vector_type(4))) float f32x4_t;

__device__ __forceinline__ float tof(float x) { return x; }
__device__ __forceinline__ float tof(__hip_bfloat16 x) { return __bfloat162float(x); }
__device__ __forceinline__ void stor(float* p, float v) { *p = v; }
__device__ __forceinline__ void stor(__hip_bfloat16* p, float v) { *p = __float2bfloat16(v); }

// low 16 bits of u as bf16 -> f32
__device__ __forceinline__ float blo(unsigned u) {
  union { unsigned u; float f; } c; c.u = u << 16; return c.f;
}
__device__ __forceinline__ float bhi(unsigned u) {
  union { unsigned u; float f; } c; c.u = u & 0xffff0000u; return c.f;
}

__device__ __forceinline__ void gload_lds16(const void* g, void* l) {
  __builtin_amdgcn_global_load_lds(
      (const __attribute__((address_space(1))) void*)g,
      (__attribute__((address_space(3))) void*)l, 16, 0, 0);
}

// ---------------- bf16 MFMA GEMM: C = act(A @ B + bias) ----------------
// A: [M,K] bf16 row-major; Bt: [N,K] bf16 row-major (B transposed).
// 4 waves in 2x2; each wave owns (FM*16)x(FN*16); BM=2*FM*16, BN=2*FN*16.
template <int BM, int BN, int FM, int FN, typename TC>
__global__ __launch_bounds__(256) void mfma_gemm(
    const __hip_bfloat16* __restrict__ A, const __hip_bfloat16* __restrict__ Bt,
    const float* __restrict__ bias, TC* __restrict__ C,
    int M, int N, int K, int act) {
  __shared__ __align__(16) __hip_bfloat16 As[2][BM][32];
  __shared__ __align__(16) __hip_bfloat16 Bs[2][BN][32];
  const int t = threadIdx.x;
  const int w = t >> 6, lane = t & 63;
  const int wm = w >> 1, wn = w & 1;
  const int bm = blockIdx.y * BM, bn = blockIdx.x * BN;
  const int lr = lane & 15, lg = lane >> 4;

  f32x4_t acc[FM][FN];
#pragma unroll
  for (int m = 0; m < FM; ++m)
#pragma unroll
    for (int n = 0; n < FN; ++n) acc[m][n] = (f32x4_t){0.f, 0.f, 0.f, 0.f};

  auto stage = [&](int buf, int kt) {
    const int k0 = kt << 5;
#pragma unroll
    for (int i = 0; i < BM / 64; ++i) {
      int L = i * 256 + t;
      gload_lds16(A + (size_t)(bm + (L >> 2)) * K + k0 + (L & 3) * 8,
                  (char*)(&As[buf][0][0]) + ((size_t)(i * 256 + w * 64)) * 16);
    }
#pragma unroll
    for (int i = 0; i < BN / 64; ++i) {
      int L = i * 256 + t;
      gload_lds16(Bt + (size_t)(bn + (L >> 2)) * K + k0 + (L & 3) * 8,
                  (char*)(&Bs[buf][0][0]) + ((size_t)(i * 256 + w * 64)) * 16);
    }
  };

  const int NT = K >> 5;
  stage(0, 0);
  __syncthreads();
  for (int kt = 0; kt < NT; ++kt) {
    const int cur = kt & 1;
    if (kt + 1 < NT) stage(cur ^ 1, kt + 1);
    bf16x8_t af[FM], bv[FN];
#pragma unroll
    for (int m = 0; m < FM; ++m)
      af[m] = *(const bf16x8_t*)&As[cur][wm * FM * 16 + m * 16 + lr][lg * 8];
#pragma unroll
    for (int n = 0; n < FN; ++n)
      bv[n] = *(const bf16x8_t*)&Bs[cur][wn * FN * 16 + n * 16 + lr][lg * 8];
#pragma unroll
    for (int m = 0; m < FM; ++m)
#pragma unroll
      for (int n = 0; n < FN; ++n)
        acc[m][n] = __builtin_amdgcn_mfma_f32_16x16x32_bf16(af[m], bv[n], acc[m][n], 0, 0, 0);
    __syncthreads();
  }

#pragma unroll
  for (int m = 0; m < FM; ++m) {
    const int row0 = bm + wm * FM * 16 + m * 16 + lg * 4;
#pragma unroll
    for (int n = 0; n < FN; ++n) {
      const int cn = bn + wn * FN * 16 + n * 16 + lr;
      const float bvv = bias ? bias[cn] : 0.f;
#pragma unroll
      for (int r = 0; r < 4; ++r) {
        float v = acc[m][n][r] + bvv;
        if (act) v = fmaxf(v, 0.f);
        stor(&C[(size_t)(row0 + r) * N + cn], v);
      }
    }
  }
}

// ---------------- split-K variant: f32 partials, no bias/act ----------------
template <int BM, int BN, int FM, int FN>
__global__ __launch_bounds__(256) void mfma_gemm_splitk(
    const __hip_bfloat16* __restrict__ A, const __hip_bfloat16* __restrict__ Bt,
    float* __restrict__ Cpart, int M, int N, int K, int KC) {
  __shared__ __align__(16) __hip_bfloat16 As[2][BM][32];
  __shared__ __align__(16) __hip_bfloat16 Bs[2][BN][32];
  const int t = threadIdx.x;
  const int w = t >> 6, lane = t & 63;
  const int wm = w >> 1, wn = w & 1;
  const int bm = blockIdx.y * BM, bn = blockIdx.x * BN;
  const int kbeg = blockIdx.z * KC;
  const int lr = lane & 15, lg = lane >> 4;

  f32x4_t acc[FM][FN];
#pragma unroll
  for (int m = 0; m < FM; ++m)
#pragma unroll
    for (int n = 0; n < FN; ++n) acc[m][n] = (f32x4_t){0.f, 0.f, 0.f, 0.f};

  auto stage = [&](int buf, int kt) {
    const int k0 = kbeg + (kt << 5);
#pragma unroll
    for (int i = 0; i < BM / 64; ++i) {
      int L = i * 256 + t;
      gload_lds16(A + (size_t)(bm + (L >> 2)) * K + k0 + (L & 3) * 8,
                  (char*)(&As[buf][0][0]) + ((size_t)(i * 256 + w * 64)) * 16);
    }
#pragma unroll
    for (int i = 0; i < BN / 64; ++i) {
      int L = i * 256 + t;
      gload_lds16(Bt + (size_t)(bn + (L >> 2)) * K + k0 + (L & 3) * 8,
                  (char*)(&Bs[buf][0][0]) + ((size_t)(i * 256 + w * 64)) * 16);
    }
  };

  const int NT = KC >> 5;
  stage(0, 0);
  __syncthreads();
  for (int kt = 0; kt < NT; ++kt) {
    const int cur = kt & 1;
    if (kt + 1 < NT) stage(cur ^ 1, kt + 1);
    bf16x8_t af[FM], bv[FN];
#pragma unroll
    for (int m = 0; m < FM; ++m)
      af[m] = *(const bf16x8_t*)&As[cur][wm * FM * 16 + m * 16 + lr][lg * 8];
#pragma unroll
    for (int n = 0; n < FN; ++n)
      bv[n] = *(const bf16x8_t*)&Bs[cur][wn * FN * 16 + n * 16 + lr][lg * 8];
#pragma unroll
    for (int m = 0; m < FM; ++m)
#pragma unroll
      for (int n = 0; n < FN; ++n)
        acc[m][n] = __builtin_amdgcn_mfma_f32_16x16x32_bf16(af[m], bv[n], acc[m][n], 0, 0, 0);
    __syncthreads();
  }

  float* Cp = Cpart + (size_t)blockIdx.z * M * N;
#pragma unroll
  for (int m = 0; m < FM; ++m) {
    const int row0 = bm + wm * FM * 16 + m * 16 + lg * 4;
#pragma unroll
    for (int n = 0; n < FN; ++n) {
      const int cn = bn + wn * FN * 16 + n * 16 + lr;
#pragma unroll
      for (int r = 0; r < 4; ++r) Cp[(size_t)(row0 + r) * N + cn] = acc[m][n][r];
    }
  }
}

__global__ void splitk_reduce_kernel(const float* __restrict__ part,
                                     __hip_bfloat16* __restrict__ outb, int MN4, int S) {
  int i = blockIdx.x * 256 + threadIdx.x;
  if (i >= MN4) return;
  float4 s = ((const float4*)part)[i];
  for (int z = 1; z < S; ++z) {
    float4 p = ((const float4*)part)[(size_t)z * MN4 + i];
    s.x += p.x; s.y += p.y; s.z += p.z; s.w += p.w;
  }
  __hip_bfloat16* o = outb + (size_t)i * 4;
  o[0] = __float2bfloat16(s.x); o[1] = __float2bfloat16(s.y);
  o[2] = __float2bfloat16(s.z); o[3] = __float2bfloat16(s.w);
}

// ---------------- transpose+convert: in f32 [K][N] -> out bf16 [N][K] ----------------
__global__ __launch_bounds__(256) void transp_kernel(const float* __restrict__ in,
                                                     __hip_bfloat16* __restrict__ out,
                                                     int K, int N) {
  __shared__ float tl[32][33];
  const int n0 = blockIdx.x * 32, k0 = blockIdx.y * 32;
  const int t = threadIdx.x;
  const int r = t >> 3, c = (t & 7) * 4;
#pragma unroll
  for (int i = 0; i < 4; ++i) tl[r][c + i] = in[(size_t)(k0 + r) * N + n0 + c + i];
  __syncthreads();
  __hip_bfloat16* op = out + (size_t)(n0 + r) * K + k0 + c;
#pragma unroll
  for (int i = 0; i < 4; ++i) op[i] = __float2bfloat16(tl[c + i][r]);
}

// ---------------- f32 -> bf16 convert (4 elems/thread) ----------------
__global__ void f2b_kernel(const float* __restrict__ in, __hip_bfloat16* __restrict__ out, int n4) {
  int i = blockIdx.x * 256 + threadIdx.x;
  if (i >= n4) return;
  float4 v = ((const float4*)in)[i];
  __hip_bfloat16* o = out + (size_t)i * 4;
  o[0] = __float2bfloat16(v.x); o[1] = __float2bfloat16(v.y);
  o[2] = __float2bfloat16(v.z); o[3] = __float2bfloat16(v.w);
}

// ---------------- small elementwise / build kernels ----------------
__global__ void img_mean_kernel(const float* __restrict__ img_cls,
                                __hip_bfloat16* __restrict__ img_mean_bf) {
  int idx = blockIdx.x * 256 + threadIdx.x;
  if (idx >= kB * kH) return;
  int b = idx / kH, c = idx - b * kH;
  const float* p = img_cls + (size_t)b * 3 * kH + c;
  img_mean_bf[idx] = __float2bfloat16((p[0] + p[kH] + p[2 * kH]) * (1.f / 3.f));
}

__global__ void winner_kernel(const int* __restrict__ business_idx, int* __restrict__ winner) {
  int i = blockIdx.x * 256 + threadIdx.x;
  if (i >= kB) return;
  atomicMax(&winner[business_idx[i] - kNU], i);  // numpy last-occurrence-wins
}

__global__ void build_user_kernel(const int* __restrict__ user_idx,
                                  const float* __restrict__ user_table,
                                  __hip_bfloat16* __restrict__ xb) {
  int i = blockIdx.x;
  int node = user_idx[i];
  for (int c = threadIdx.x; c < kH; c += blockDim.x)
    xb[(size_t)node * kH + c] = __float2bfloat16(user_table[(size_t)node * kH + c]);
}

__global__ void build_biz_kernel(const int* __restrict__ winner,
                                 const float* __restrict__ text_emb,
                                 const float* __restrict__ img_emb,
                                 const float* __restrict__ biz_feats,
                                 const float* __restrict__ W_bf,
                                 const float* __restrict__ b_bf,
                                 const float* __restrict__ biz_table,
                                 __hip_bfloat16* __restrict__ xb) {
  int m = blockIdx.x;
  int w = winner[m];
  if (w < 0) return;
  int node = kNU + m;
  float f0 = biz_feats[w * 3], f1 = biz_feats[w * 3 + 1], f2 = biz_feats[w * 3 + 2];
  for (int c = threadIdx.x; c < kH; c += blockDim.x) {
    float meta = f0 * W_bf[c] + f1 * W_bf[kH + c] + f2 * W_bf[2 * kH + c] + b_bf[c];
    float v = (text_emb[(size_t)w * kH + c] + img_emb[(size_t)w * kH + c] + meta +
               biz_table[(size_t)m * kH + c]) * 0.25f;
    xb[(size_t)node * kH + c] = __float2bfloat16(v);
  }
}

// ---------------- CSR build (edges grouped by dst) ----------------
__global__ void deg_kernel(const int* __restrict__ ei, int* __restrict__ deg) {
  int e = blockIdx.x * 256 + threadIdx.x;
  if (e >= kET) return;
  int dst = (e < kE) ? ei[kE + e] : (e - kE);
  atomicAdd(&deg[dst], 1);
}

__global__ __launch_bounds__(1024) void scan_kernel(const int* __restrict__ deg,
                                                    int* __restrict__ rowptr,
                                                    int* __restrict__ cursor) {
  __shared__ int sums[1024];
  int t = threadIdx.x;
  int v0 = deg[t * 3], v1 = deg[t * 3 + 1], v2 = deg[t * 3 + 2];
  int s = v0 + v1 + v2;
  sums[t] = s;
  __syncthreads();
  for (int o = 1; o < 1024; o <<= 1) {
    int xv = (t >= o) ? sums[t - o] : 0;
    __syncthreads();
    sums[t] += xv;
    __syncthreads();
  }
  int excl = sums[t] - s;
  rowptr[t * 3] = excl;          cursor[t * 3] = excl;
  rowptr[t * 3 + 1] = excl + v0; cursor[t * 3 + 1] = excl + v0;
  rowptr[t * 3 + 2] = excl + v0 + v1; cursor[t * 3 + 2] = excl + v0 + v1;
  if (t == 1023) rowptr[kNN] = excl + s;
}

__global__ void fill_kernel(const int* __restrict__ ei, int* __restrict__ cursor,
                            int* __restrict__ cols) {
  int e = blockIdx.x * 256 + threadIdx.x;
  if (e >= kET) return;
  int src, dst;
  if (e < kE) { src = ei[e]; dst = ei[kE + e]; } else { src = dst = e - kE; }
  int pos = atomicAdd(&cursor[dst], 1);
  cols[pos] = src;
}

// ---------------- attention scores: s = sum(h * att, -1) ----------------
__global__ __launch_bounds__(256) void scores_kernel(
    const __hip_bfloat16* __restrict__ h, const float* __restrict__ att_src,
    const float* __restrict__ att_dst, float* __restrict__ s_src,
    float* __restrict__ s_dst, int total, int heads) {
  int gw = (blockIdx.x * 256 + threadIdx.x) >> 6;
  int lane = threadIdx.x & 63;
  if (gw >= total) return;
  int hd = gw % heads;
  const unsigned* hp = (const unsigned*)(h + (size_t)gw * kH);
  const float* as = att_src + (size_t)hd * kH;
  const float* ad = att_dst + (size_t)hd * kH;
  float ss = 0.f, sd = 0.f;
  for (int u = lane; u < kH / 2; u += 64) {
    unsigned v = hp[u];
    float f0 = blo(v), f1 = bhi(v);
    int c = u * 2;
    ss = fmaf(f0, as[c], fmaf(f1, as[c + 1], ss));
    sd = fmaf(f0, ad[c], fmaf(f1, ad[c + 1], sd));
  }
#pragma unroll
  for (int o = 32; o; o >>= 1) { ss += __shfl_down(ss, o); sd += __shfl_down(sd, o); }
  if (lane == 0) { s_src[gw] = ss; s_dst[gw] = sd; }
}

// ---------------- GAT segment softmax + aggregation ----------------
// one block (192 threads = 3 waves) per (node, head); thread t owns channels 4t..4t+3
__global__ __launch_bounds__(192) void gat_agg_kernel(
    const int* __restrict__ rowptr, const int* __restrict__ cols,
    const float* __restrict__ s_src, const float* __restrict__ s_dst,
    const __hip_bfloat16* __restrict__ h, const float* __restrict__ bias,
    int heads, int act, __hip_bfloat16* __restrict__ out_bf, float* __restrict__ out_f) {
  __shared__ float red[3];
  const int bid = blockIdx.x;
  const int n = bid / heads;
  const int hd = bid - n * heads;
  const int beg = rowptr[n], end = rowptr[n + 1];
  const float sdv = s_dst[(size_t)n * heads + hd];
  const int t = threadIdx.x, lane = t & 63, wid = t >> 6;

  // pass 1: segment max
  float m = -3.402823466e38f;
  for (int i = beg + t; i < end; i += 192) {
    float e = s_src[(size_t)cols[i] * heads + hd] + sdv;
    e = (e > 0.f) ? e : 0.2f * e;
    m = fmaxf(m, e);
  }
#pragma unroll
  for (int o = 32; o; o >>= 1) m = fmaxf(m, __shfl_down(m, o));
  if (lane == 0) red[wid] = m;
  __syncthreads();
  m = fmaxf(fmaxf(red[0], red[1]), red[2]);
  __syncthreads();

  // pass 2: denom
  float dsum = 0.f;
  for (int i = beg + t; i < end; i += 192) {
    float e = s_src[(size_t)cols[i] * heads + hd] + sdv;
    e = (e > 0.f) ? e : 0.2f * e;
    dsum += expf(e - m);
  }
#pragma unroll
  for (int o = 32; o; o >>= 1) dsum += __shfl_down(dsum, o);
  if (lane == 0) red[wid] = dsum;
  __syncthreads();
  dsum = red[0] + red[1] + red[2] + 1e-16f;
  const float rdsum = 1.f / dsum;

  // pass 3: weighted aggregation; 8B vector loads
  float a0 = 0.f, a1 = 0.f, a2 = 0.f, a3 = 0.f;
  const size_t hs = (size_t)heads * kH;
  const size_t coff = (size_t)hd * kH + (size_t)t * 4;
  for (int i = beg; i < end; ++i) {
    int src = cols[i];
    float e = s_src[(size_t)src * heads + hd] + sdv;
    e = (e > 0.f) ? e : 0.2f * e;
    float wgt = expf(e - m) * rdsum;
    uint2 v = *(const uint2*)(h + (size_t)src * hs + coff);
    a0 = fmaf(wgt, blo(v.x), a0);
    a1 = fmaf(wgt, bhi(v.x), a1);
    a2 = fmaf(wgt, blo(v.y), a2);
    a3 = fmaf(wgt, bhi(v.y), a3);
  }
  const int cbase = hd * kH + t * 4;
  float v0 = a0 + bias[cbase + 0];
  float v1 = a1 + bias[cbase + 1];
  float v2 = a2 + bias[cbase + 2];
  float v3 = a3 + bias[cbase + 3];
  if (act) {
    v0 = fmaxf(v0, 0.f); v1 = fmaxf(v1, 0.f); v2 = fmaxf(v2, 0.f); v3 = fmaxf(v3, 0.f);
  }
  size_t ob = (size_t)n * hs + cbase;
  if (out_bf) {
    out_bf[ob + 0] = __float2bfloat16(v0);
    out_bf[ob + 1] = __float2bfloat16(v1);
    out_bf[ob + 2] = __float2bfloat16(v2);
    out_bf[ob + 3] = __float2bfloat16(v3);
  } else {
    out_f[ob + 0] = v0; out_f[ob + 1] = v1; out_f[ob + 2] = v2; out_f[ob + 3] = v3;
  }
}

// ---------------- MLP head ----------------
__global__ void cat_kernel(const float* __restrict__ xf, const float* __restrict__ text_emb,
                           const float* __restrict__ img_emb, const int* __restrict__ user_idx,
                           const int* __restrict__ business_idx, __hip_bfloat16* __restrict__ cat) {
  int b = blockIdx.x;
  int u = user_idx[b], z = business_idx[b];
  __hip_bfloat16* crow = cat + (size_t)b * 4 * kH;
  for (int c = threadIdx.x; c < kH; c += blockDim.x) {
    crow[c] = __float2bfloat16(xf[(size_t)u * kH + c]);
    crow[kH + c] = __float2bfloat16(xf[(size_t)z * kH + c]);
    crow[2 * kH + c] = __float2bfloat16(text_emb[(size_t)b * kH + c]);
    crow[3 * kH + c] = __float2bfloat16(img_emb[(size_t)b * kH + c]);
  }
}

__global__ __launch_bounds__(256) void final_kernel(const float* __restrict__ m2,
                                                    const float* __restrict__ Wf3,
                                                    const float* __restrict__ bf3,
                                                    float* __restrict__ out) {
  int b = (blockIdx.x * 256 + threadIdx.x) >> 6;
  int lane = threadIdx.x & 63;
  if (b >= kB) return;
  float s = 0.f;
  for (int c = lane; c < kH; c += 64) s = fmaf(m2[(size_t)b * kH + c], Wf3[c], s);
#pragma unroll
  for (int o = 32; o; o >>= 1) s += __shfl_down(s, o);
  if (lane == 0) out[b] = s + bf3[0];
}

}  // namespace

extern "C" void kernel_launch(void* const* d_in, const int* in_sizes, int n_in,
                              void* d_out, int out_size, void* d_ws, size_t ws_size,
                              hipStream_t stream) {
  const float* text_cls = (const float*)d_in[0];
  const float* img_cls = (const float*)d_in[1];
  const float* biz_feats = (const float*)d_in[2];
  const float* W_text = (const float*)d_in[3];
  const float* b_text = (const float*)d_in[4];
  const float* W_img = (const float*)d_in[5];
  const float* b_img = (const float*)d_in[6];
  const float* W_bf = (const float*)d_in[7];
  const float* b_bf = (const float*)d_in[8];
  const float* user_table = (const float*)d_in[9];
  const float* biz_table = (const float*)d_in[10];
  const float* W1 = (const float*)d_in[11];
  const float* att_src1 = (const float*)d_in[12];
  const float* att_dst1 = (const float*)d_in[13];
  const float* b1 = (const float*)d_in[14];
  const float* W2 = (const float*)d_in[15];
  const float* att_src2 = (const float*)d_in[16];
  const float* att_dst2 = (const float*)d_in[17];
  const float* b2 = (const float*)d_in[18];
  const float* Wf1 = (const float*)d_in[19];
  const float* bf1 = (const float*)d_in[20];
  const float* Wf2 = (const float*)d_in[21];
  const float* bf2 = (const float*)d_in[22];
  const float* Wf3 = (const float*)d_in[23];
  const float* bf3 = (const float*)d_in[24];
  const int* user_idx = (const int*)d_in[25];
  const int* business_idx = (const int*)d_in[26];
  const int* edge_index = (const int*)d_in[27];
  float* out = (float*)d_out;
  (void)in_sizes; (void)n_in; (void)out_size; (void)ws_size;

  char* base = (char*)d_ws;
  size_t off = 0;
  auto alloc = [&](size_t bytes) -> void* {
    void* p = base + off;
    off = (off + bytes + 255) & ~(size_t)255;
    return p;
  };
  __hip_bfloat16* xb = (__hip_bfloat16*)alloc((size_t)kNN * kH * 2);
  __hip_bfloat16* text_bf = (__hip_bfloat16*)alloc((size_t)kB * kH * 2);
  __hip_bfloat16* imgm_bf = (__hip_bfloat16*)alloc((size_t)kB * kH * 2);
  float* text_emb = (float*)alloc((size_t)kB * kH * 4);
  float* img_emb = (float*)alloc((size_t)kB * kH * 4);
  __hip_bfloat16* Wtt = (__hip_bfloat16*)alloc((size_t)kH * kH * 2);
  __hip_bfloat16* Wit = (__hip_bfloat16*)alloc((size_t)kH * kH * 2);
  __hip_bfloat16* W1t = (__hip_bfloat16*)alloc((size_t)kHeads * kH * kH * 2);
  __hip_bfloat16* W2t = (__hip_bfloat16*)alloc((size_t)kH * kHeads * kH * 2);
  __hip_bfloat16* Wf1t = (__hip_bfloat16*)alloc((size_t)2 * kH * 4 * kH * 2);
  __hip_bfloat16* Wf2t = (__hip_bfloat16*)alloc((size_t)kH * 2 * kH * 2);
  __hip_bfloat16* h1 = (__hip_bfloat16*)alloc((size_t)kNN * kHeads * kH * 2);
  __hip_bfloat16* x2 = (__hip_bfloat16*)alloc((size_t)kNN * kHeads * kH * 2);
  __hip_bfloat16* h2 = (__hip_bfloat16*)alloc((size_t)kNN * kH * 2);
  float* xf = (float*)alloc((size_t)kNN * kH * 4);
  float* s1s = (float*)alloc((size_t)kNN * kHeads * 4);
  float* s1d = (float*)alloc((size_t)kNN * kHeads * 4);
  float* s2s = (float*)alloc((size_t)kNN * 4);
  float* s2d = (float*)alloc((size_t)kNN * 4);
  __hip_bfloat16* catb = (__hip_bfloat16*)alloc((size_t)kB * 4 * kH * 2);
  __hip_bfloat16* m1 = (__hip_bfloat16*)alloc((size_t)kB * 2 * kH * 2);
  float* m2 = (float*)alloc((size_t)kB * kH * 4);
  int* deg = (int*)alloc((size_t)kNN * 4);
  int* rowptr = (int*)alloc((size_t)(kNN + 1) * 4);
  int* cursor = (int*)alloc((size_t)kNN * 4);
  int* cols = (int*)alloc((size_t)kET * 4);
  int* winner = (int*)alloc((size_t)kNB * 4);

  // split-K partials aliased over h1 (dead after scores1/agg1):
  // kSplitK * kNN * kH * 4 bytes == kNN * kHeads*kH * 2 bytes (exact fit)
  float* part = (float*)h1;

  hipMemsetAsync(xb, 0, (size_t)kNN * kH * 2, stream);
  hipMemsetAsync(deg, 0, (size_t)kNN * 4, stream);
  hipMemsetAsync(winner, 0xFF, (size_t)kNB * 4, stream);

  // weight transposes (f32 [K][N] -> bf16 [N][K])
  transp_kernel<<<dim3(kH / 32, kH / 32), 256, 0, stream>>>(W_text, Wtt, kH, kH);
  transp_kernel<<<dim3(kH / 32, kH / 32), 256, 0, stream>>>(W_img, Wit, kH, kH);
  transp_kernel<<<dim3(kHeads * kH / 32, kH / 32), 256, 0, stream>>>(W1, W1t, kH, kHeads * kH);
  transp_kernel<<<dim3(kH / 32, kHeads * kH / 32), 256, 0, stream>>>(W2, W2t, kHeads * kH, kH);
  transp_kernel<<<dim3(2 * kH / 32, 4 * kH / 32), 256, 0, stream>>>(Wf1, Wf1t, 4 * kH, 2 * kH);
  transp_kernel<<<dim3(kH / 32, 2 * kH / 32), 256, 0, stream>>>(Wf2, Wf2t, 2 * kH, kH);

  // input conversions
  f2b_kernel<<<(kB * kH / 4 + 255) / 256, 256, 0, stream>>>(text_cls, text_bf, kB * kH / 4);
  img_mean_kernel<<<(kB * kH + 255) / 256, 256, 0, stream>>>(img_cls, imgm_bf);

  // encoders (bf16 MFMA, f32 out)
  mfma_gemm<64, 64, 2, 2, float><<<dim3(kH / 64, kB / 64), 256, 0, stream>>>(
      text_bf, Wtt, b_text, text_emb, kB, kH, kH, 0);
  mfma_gemm<64, 64, 2, 2, float><<<dim3(kH / 64, kB / 64), 256, 0, stream>>>(
      imgm_bf, Wit, b_img, img_emb, kB, kH, kH, 0);

  // node features
  winner_kernel<<<(kB + 255) / 256, 256, 0, stream>>>(business_idx, winner);
  build_user_kernel<<<kB, 256, 0, stream>>>(user_idx, user_table, xb);
  build_biz_kernel<<<kNB, 256, 0, stream>>>(winner, text_emb, img_emb, biz_feats, W_bf, b_bf,
                                            biz_table, xb);

  // CSR
  deg_kernel<<<(kET + 255) / 256, 256, 0, stream>>>(edge_index, deg);
  scan_kernel<<<1, 1024, 0, stream>>>(deg, rowptr, cursor);
  fill_kernel<<<(kET + 255) / 256, 256, 0, stream>>>(edge_index, cursor, cols);

  // GAT layer 1 (8 heads)
  mfma_gemm<128, 128, 4, 4, __hip_bfloat16><<<dim3(kHeads * kH / 128, kNN / 128), 256, 0, stream>>>(
      xb, W1t, nullptr, h1, kNN, kHeads * kH, kH, 0);
  scores_kernel<<<(kNN * kHeads + 3) / 4, 256, 0, stream>>>(h1, att_src1, att_dst1, s1s, s1d,
                                                            kNN * kHeads, kHeads);
  gat_agg_kernel<<<kNN * kHeads, 192, 0, stream>>>(rowptr, cols, s1s, s1d, h1, b1, kHeads, 1,
                                                   x2, nullptr);

  // GAT layer 2 (1 head): split-K over K=6144, partials over dead h1, then reduce
  mfma_gemm_splitk<128, 128, 4, 4><<<dim3(kH / 128, kNN / 128, kSplitK), 256, 0, stream>>>(
      x2, W2t, part, kNN, kH, kHeads * kH, kHeads * kH / kSplitK);
  splitk_reduce_kernel<<<(kNN * kH / 4 + 255) / 256, 256, 0, stream>>>(
      part, h2, kNN * kH / 4, kSplitK);
  scores_kernel<<<(kNN + 3) / 4, 256, 0, stream>>>(h2, att_src2, att_dst2, s2s, s2d, kNN, 1);
  gat_agg_kernel<<<kNN, 192, 0, stream>>>(rowptr, cols, s2s, s2d, h2, b2, 1, 0, nullptr, xf);

  // MLP head
  cat_kernel<<<kB, 256, 0, stream>>>(xf, text_emb, img_emb, user_idx, business_idx, catb);
  mfma_gemm<64, 64, 2, 2, __hip_bfloat16><<<dim3(2 * kH / 64, kB / 64), 256, 0, stream>>>(
      catb, Wf1t, bf1, m1, kB, 2 * kH, 4 * kH, 1);
  mfma_gemm<64, 64, 2, 2, float><<<dim3(kH / 64, kB / 64), 256, 0, stream>>>(
      m1, Wf2t, bf2, m2, kB, kH, 2 * kH, 1);
  final_kernel<<<(kB * 64 + 255) / 256, 256, 0, stream>>>(m2, Wf3, bf3, out);
}

// Round 4
// 323.478 us; speedup vs baseline: 4.0307x; 1.0779x over previous
//
#include <hip/hip_runtime.h>
#include <hip/hip_bf16.h>

namespace {

constexpr int kB = 1024;      // batch
constexpr int kNU = 1024;     // num users
constexpr int kNB = 2048;     // num businesses
constexpr int kNN = 3072;     // total nodes
constexpr int kE = 16384;     // raw edges
constexpr int kET = kE + kNN; // edges + self loops = 19456
constexpr int kH = 768;
constexpr int kHeads = 8;
constexpr int kSplitK = 4;    // GAT2 split-K factor

typedef __attribute__((ext_vector_type(8))) short bf16x8_t;
typedef __attribute__((ext_vector_type(4))) float f32x4_t;

__device__ __forceinline__ float tof(float x) { return x; }
__device__ __forceinline__ float tof(__hip_bfloat16 x) { return __bfloat162float(x); }
__device__ __forceinline__ void stor(float* p, float v) { *p = v; }
__device__ __forceinline__ void stor(__hip_bfloat16* p, float v) { *p = __float2bfloat16(v); }

__device__ __forceinline__ float blo(unsigned u) {
  union { unsigned u; float f; } c; c.u = u << 16; return c.f;
}
__device__ __forceinline__ float bhi(unsigned u) {
  union { unsigned u; float f; } c; c.u = u & 0xffff0000u; return c.f;
}

__device__ __forceinline__ void gload_lds16(const void* g, void* l) {
  __builtin_amdgcn_global_load_lds(
      (const __attribute__((address_space(1))) void*)g,
      (__attribute__((address_space(3))) void*)l, 16, 0, 0);
}

// ---------------- shared GEMM body ----------------
// A: [M,K] bf16 row-major; Bt: [N,K] bf16 row-major. 4 waves 2x2.
template <int BM, int BN, int FM, int FN, typename TC>
__device__ __forceinline__ void gemm_body(
    const __hip_bfloat16* __restrict__ A, const __hip_bfloat16* __restrict__ Bt,
    const float* __restrict__ bias, TC* __restrict__ C,
    int M, int N, int K, int act, int bx, int by) {
  __shared__ __align__(16) __hip_bfloat16 As[2][BM][32];
  __shared__ __align__(16) __hip_bfloat16 Bs[2][BN][32];
  const int t = threadIdx.x;
  const int w = t >> 6, lane = t & 63;
  const int wm = w >> 1, wn = w & 1;
  const int bm = by * BM, bn = bx * BN;
  const int lr = lane & 15, lg = lane >> 4;

  f32x4_t acc[FM][FN];
#pragma unroll
  for (int m = 0; m < FM; ++m)
#pragma unroll
    for (int n = 0; n < FN; ++n) acc[m][n] = (f32x4_t){0.f, 0.f, 0.f, 0.f};

  auto stage = [&](int buf, int kt) {
    const int k0 = kt << 5;
#pragma unroll
    for (int i = 0; i < BM / 64; ++i) {
      int L = i * 256 + t;
      gload_lds16(A + (size_t)(bm + (L >> 2)) * K + k0 + (L & 3) * 8,
                  (char*)(&As[buf][0][0]) + ((size_t)(i * 256 + w * 64)) * 16);
    }
#pragma unroll
    for (int i = 0; i < BN / 64; ++i) {
      int L = i * 256 + t;
      gload_lds16(Bt + (size_t)(bn + (L >> 2)) * K + k0 + (L & 3) * 8,
                  (char*)(&Bs[buf][0][0]) + ((size_t)(i * 256 + w * 64)) * 16);
    }
  };

  const int NT = K >> 5;
  stage(0, 0);
  __syncthreads();
  for (int kt = 0; kt < NT; ++kt) {
    const int cur = kt & 1;
    if (kt + 1 < NT) stage(cur ^ 1, kt + 1);
    bf16x8_t af[FM], bv[FN];
#pragma unroll
    for (int m = 0; m < FM; ++m)
      af[m] = *(const bf16x8_t*)&As[cur][wm * FM * 16 + m * 16 + lr][lg * 8];
#pragma unroll
    for (int n = 0; n < FN; ++n)
      bv[n] = *(const bf16x8_t*)&Bs[cur][wn * FN * 16 + n * 16 + lr][lg * 8];
#pragma unroll
    for (int m = 0; m < FM; ++m)
#pragma unroll
      for (int n = 0; n < FN; ++n)
        acc[m][n] = __builtin_amdgcn_mfma_f32_16x16x32_bf16(af[m], bv[n], acc[m][n], 0, 0, 0);
    __syncthreads();
  }

#pragma unroll
  for (int m = 0; m < FM; ++m) {
    const int row0 = bm + wm * FM * 16 + m * 16 + lg * 4;
#pragma unroll
    for (int n = 0; n < FN; ++n) {
      const int cn = bn + wn * FN * 16 + n * 16 + lr;
      const float bvv = bias ? bias[cn] : 0.f;
#pragma unroll
      for (int r = 0; r < 4; ++r) {
        float v = acc[m][n][r] + bvv;
        if (act) v = fmaxf(v, 0.f);
        stor(&C[(size_t)(row0 + r) * N + cn], v);
      }
    }
  }
}

// bijective XCD swizzle over x*y grid (nwg must be divisible by 8)
__device__ __forceinline__ void swz_xy(bool mfast, int& bx, int& by) {
  const int nwg = gridDim.x * gridDim.y;
  const int orig = blockIdx.y * gridDim.x + blockIdx.x;
  const int swz = (orig & 7) * (nwg >> 3) + (orig >> 3);
  if (mfast) { by = swz % gridDim.y; bx = swz / gridDim.y; }
  else       { bx = swz % gridDim.x; by = swz / gridDim.x; }
}

template <int BM, int BN, int FM, int FN, typename TC, bool MFAST>
__global__ __launch_bounds__(256) void mfma_gemm(
    const __hip_bfloat16* __restrict__ A, const __hip_bfloat16* __restrict__ Bt,
    const float* __restrict__ bias, TC* __restrict__ C,
    int M, int N, int K, int act) {
  int bx, by;
  swz_xy(MFAST, bx, by);
  gemm_body<BM, BN, FM, FN, TC>(A, Bt, bias, C, M, N, K, act, bx, by);
}

// dual-batched encoder GEMM (blockIdx.z selects problem; same dims)
template <int BM, int BN, int FM, int FN>
__global__ __launch_bounds__(256) void mfma_gemm_dual(
    const __hip_bfloat16* __restrict__ A0, const __hip_bfloat16* __restrict__ Bt0,
    const float* __restrict__ bias0, float* __restrict__ C0,
    const __hip_bfloat16* __restrict__ A1, const __hip_bfloat16* __restrict__ Bt1,
    const float* __restrict__ bias1, float* __restrict__ C1,
    int M, int N, int K) {
  int bx, by;
  swz_xy(true, bx, by);
  const __hip_bfloat16* A = blockIdx.z ? A1 : A0;
  const __hip_bfloat16* Bt = blockIdx.z ? Bt1 : Bt0;
  const float* bias = blockIdx.z ? bias1 : bias0;
  float* C = blockIdx.z ? C1 : C0;
  gemm_body<BM, BN, FM, FN, float>(A, Bt, bias, C, M, N, K, 0, bx, by);
}

// split-K variant: f32 partials
template <int BM, int BN, int FM, int FN>
__global__ __launch_bounds__(256) void mfma_gemm_splitk(
    const __hip_bfloat16* __restrict__ A, const __hip_bfloat16* __restrict__ Bt,
    float* __restrict__ Cpart, int M, int N, int K, int KC) {
  __shared__ __align__(16) __hip_bfloat16 As[2][BM][32];
  __shared__ __align__(16) __hip_bfloat16 Bs[2][BN][32];
  int bx, by;
  swz_xy(false, bx, by);
  const int t = threadIdx.x;
  const int w = t >> 6, lane = t & 63;
  const int wm = w >> 1, wn = w & 1;
  const int bm = by * BM, bn = bx * BN;
  const int kbeg = blockIdx.z * KC;
  const int lr = lane & 15, lg = lane >> 4;

  f32x4_t acc[FM][FN];
#pragma unroll
  for (int m = 0; m < FM; ++m)
#pragma unroll
    for (int n = 0; n < FN; ++n) acc[m][n] = (f32x4_t){0.f, 0.f, 0.f, 0.f};

  auto stage = [&](int buf, int kt) {
    const int k0 = kbeg + (kt << 5);
#pragma unroll
    for (int i = 0; i < BM / 64; ++i) {
      int L = i * 256 + t;
      gload_lds16(A + (size_t)(bm + (L >> 2)) * K + k0 + (L & 3) * 8,
                  (char*)(&As[buf][0][0]) + ((size_t)(i * 256 + w * 64)) * 16);
    }
#pragma unroll
    for (int i = 0; i < BN / 64; ++i) {
      int L = i * 256 + t;
      gload_lds16(Bt + (size_t)(bn + (L >> 2)) * K + k0 + (L & 3) * 8,
                  (char*)(&Bs[buf][0][0]) + ((size_t)(i * 256 + w * 64)) * 16);
    }
  };

  const int NT = KC >> 5;
  stage(0, 0);
  __syncthreads();
  for (int kt = 0; kt < NT; ++kt) {
    const int cur = kt & 1;
    if (kt + 1 < NT) stage(cur ^ 1, kt + 1);
    bf16x8_t af[FM], bv[FN];
#pragma unroll
    for (int m = 0; m < FM; ++m)
      af[m] = *(const bf16x8_t*)&As[cur][wm * FM * 16 + m * 16 + lr][lg * 8];
#pragma unroll
    for (int n = 0; n < FN; ++n)
      bv[n] = *(const bf16x8_t*)&Bs[cur][wn * FN * 16 + n * 16 + lr][lg * 8];
#pragma unroll
    for (int m = 0; m < FM; ++m)
#pragma unroll
      for (int n = 0; n < FN; ++n)
        acc[m][n] = __builtin_amdgcn_mfma_f32_16x16x32_bf16(af[m], bv[n], acc[m][n], 0, 0, 0);
    __syncthreads();
  }

  float* Cp = Cpart + (size_t)blockIdx.z * M * N;
#pragma unroll
  for (int m = 0; m < FM; ++m) {
    const int row0 = bm + wm * FM * 16 + m * 16 + lg * 4;
#pragma unroll
    for (int n = 0; n < FN; ++n) {
      const int cn = bn + wn * FN * 16 + n * 16 + lr;
#pragma unroll
      for (int r = 0; r < 4; ++r) Cp[(size_t)(row0 + r) * N + cn] = acc[m][n][r];
    }
  }
}

__global__ void splitk_reduce_kernel(const float* __restrict__ part,
                                     __hip_bfloat16* __restrict__ outb, int MN4, int S) {
  int i = blockIdx.x * 256 + threadIdx.x;
  if (i >= MN4) return;
  float4 s = ((const float4*)part)[i];
  for (int z = 1; z < S; ++z) {
    float4 p = ((const float4*)part)[(size_t)z * MN4 + i];
    s.x += p.x; s.y += p.y; s.z += p.z; s.w += p.w;
  }
  __hip_bfloat16* o = outb + (size_t)i * 4;
  o[0] = __float2bfloat16(s.x); o[1] = __float2bfloat16(s.y);
  o[2] = __float2bfloat16(s.z); o[3] = __float2bfloat16(s.w);
}

// ---------------- batched transpose+convert: f32 [K][N] -> bf16 [N][K] ----------------
struct TJobs {
  const float* in[6];
  __hip_bfloat16* out[6];
  int K[6];
  int N[6];
  int start[7];
};

__global__ __launch_bounds__(256) void transp_all_kernel(TJobs j) {
  __shared__ float tl[32][33];
  const int bid = blockIdx.x;
  int idx = 0;
#pragma unroll
  for (int q = 1; q < 6; ++q)
    if (bid >= j.start[q]) idx = q;
  const int tile = bid - j.start[idx];
  const int N = j.N[idx], K = j.K[idx];
  const int tilesN = N >> 5;
  const int n0 = (tile % tilesN) << 5, k0 = (tile / tilesN) << 5;
  const float* in = j.in[idx];
  __hip_bfloat16* out = j.out[idx];
  const int t = threadIdx.x;
  const int r = t >> 3, c = (t & 7) * 4;
#pragma unroll
  for (int i = 0; i < 4; ++i) tl[r][c + i] = in[(size_t)(k0 + r) * N + n0 + c + i];
  __syncthreads();
  __hip_bfloat16* op = out + (size_t)(n0 + r) * K + k0 + c;
#pragma unroll
  for (int i = 0; i < 4; ++i) op[i] = __float2bfloat16(tl[c + i][r]);
}

// ---------------- input prep: text f32->bf16 + img 3-view mean->bf16 ----------------
__global__ void prep_inputs_kernel(const float* __restrict__ text_cls,
                                   const float* __restrict__ img_cls,
                                   __hip_bfloat16* __restrict__ text_bf,
                                   __hip_bfloat16* __restrict__ imgm_bf) {
  int idx = blockIdx.x * 256 + threadIdx.x;
  if (idx >= kB * kH) return;
  text_bf[idx] = __float2bfloat16(text_cls[idx]);
  int b = idx / kH, c = idx - b * kH;
  const float* p = img_cls + (size_t)b * 3 * kH + c;
  imgm_bf[idx] = __float2bfloat16((p[0] + p[kH] + p[2 * kH]) * (1.f / 3.f));
}

// ---------------- degree count + winner (merged) ----------------
__global__ void deg_winner_kernel(const int* __restrict__ ei, int* __restrict__ deg,
                                  const int* __restrict__ business_idx,
                                  int* __restrict__ winner) {
  int e = blockIdx.x * 256 + threadIdx.x;
  if (e < kET) {
    int dst = (e < kE) ? ei[kE + e] : (e - kE);
    atomicAdd(&deg[dst], 1);
  }
  if (e < kB) atomicMax(&winner[business_idx[e] - kNU], e);  // last-occurrence-wins
}

__global__ __launch_bounds__(1024) void scan_kernel(const int* __restrict__ deg,
                                                    int* __restrict__ rowptr,
                                                    int* __restrict__ cursor) {
  __shared__ int sums[1024];
  int t = threadIdx.x;
  int v0 = deg[t * 3], v1 = deg[t * 3 + 1], v2 = deg[t * 3 + 2];
  int s = v0 + v1 + v2;
  sums[t] = s;
  __syncthreads();
  for (int o = 1; o < 1024; o <<= 1) {
    int xv = (t >= o) ? sums[t - o] : 0;
    __syncthreads();
    sums[t] += xv;
    __syncthreads();
  }
  int excl = sums[t] - s;
  rowptr[t * 3] = excl;          cursor[t * 3] = excl;
  rowptr[t * 3 + 1] = excl + v0; cursor[t * 3 + 1] = excl + v0;
  rowptr[t * 3 + 2] = excl + v0 + v1; cursor[t * 3 + 2] = excl + v0 + v1;
  if (t == 1023) rowptr[kNN] = excl + s;
}

__global__ void fill_kernel(const int* __restrict__ ei, int* __restrict__ cursor,
                            int* __restrict__ cols) {
  int e = blockIdx.x * 256 + threadIdx.x;
  if (e >= kET) return;
  int src, dst;
  if (e < kE) { src = ei[e]; dst = ei[kE + e]; } else { src = dst = e - kE; }
  int pos = atomicAdd(&cursor[dst], 1);
  cols[pos] = src;
}

// ---------------- node feature build (users + businesses merged) ----------------
__global__ void build_x_kernel(const int* __restrict__ user_idx,
                               const float* __restrict__ user_table,
                               const int* __restrict__ winner,
                               const float* __restrict__ text_emb,
                               const float* __restrict__ img_emb,
                               const float* __restrict__ biz_feats,
                               const float* __restrict__ W_bf,
                               const float* __restrict__ b_bf,
                               const float* __restrict__ biz_table,
                               __hip_bfloat16* __restrict__ xb) {
  int b = blockIdx.x;
  if (b < kNU) {
    int node = user_idx[b];
    for (int c = threadIdx.x; c < kH; c += blockDim.x)
      xb[(size_t)node * kH + c] = __float2bfloat16(user_table[(size_t)node * kH + c]);
  } else {
    int m = b - kNU;
    int w = winner[m];
    if (w < 0) return;
    int node = kNU + m;
    float f0 = biz_feats[w * 3], f1 = biz_feats[w * 3 + 1], f2 = biz_feats[w * 3 + 2];
    for (int c = threadIdx.x; c < kH; c += blockDim.x) {
      float meta = f0 * W_bf[c] + f1 * W_bf[kH + c] + f2 * W_bf[2 * kH + c] + b_bf[c];
      float v = (text_emb[(size_t)w * kH + c] + img_emb[(size_t)w * kH + c] + meta +
                 biz_table[(size_t)m * kH + c]) * 0.25f;
      xb[(size_t)node * kH + c] = __float2bfloat16(v);
    }
  }
}

// ---------------- attention scores: s = sum(h * att, -1) ----------------
__global__ __launch_bounds__(256) void scores_kernel(
    const __hip_bfloat16* __restrict__ h, const float* __restrict__ att_src,
    const float* __restrict__ att_dst, float* __restrict__ s_src,
    float* __restrict__ s_dst, int total, int heads) {
  int gw = (blockIdx.x * 256 + threadIdx.x) >> 6;
  int lane = threadIdx.x & 63;
  if (gw >= total) return;
  int hd = gw % heads;
  const unsigned* hp = (const unsigned*)(h + (size_t)gw * kH);
  const float* as = att_src + (size_t)hd * kH;
  const float* ad = att_dst + (size_t)hd * kH;
  float ss = 0.f, sd = 0.f;
  for (int u = lane; u < kH / 2; u += 64) {
    unsigned v = hp[u];
    float f0 = blo(v), f1 = bhi(v);
    int c = u * 2;
    ss = fmaf(f0, as[c], fmaf(f1, as[c + 1], ss));
    sd = fmaf(f0, ad[c], fmaf(f1, ad[c + 1], sd));
  }
#pragma unroll
  for (int o = 32; o; o >>= 1) { ss += __shfl_down(ss, o); sd += __shfl_down(sd, o); }
  if (lane == 0) { s_src[gw] = ss; s_dst[gw] = sd; }
}

// ---------------- GAT segment softmax + aggregation (wave per (node,head)) ----------
// block = 256 threads = 4 waves; wave handles one (node,head); lane owns 12 channels
__global__ __launch_bounds__(256) void gat_agg_kernel(
    const int* __restrict__ rowptr, const int* __restrict__ cols,
    const float* __restrict__ s_src, const float* __restrict__ s_dst,
    const __hip_bfloat16* __restrict__ h, const float* __restrict__ bias,
    int heads, int act, __hip_bfloat16* __restrict__ out_bf, float* __restrict__ out_f,
    int total) {
  const int pair = blockIdx.x * 4 + (threadIdx.x >> 6);
  if (pair >= total) return;
  const int lane = threadIdx.x & 63;
  const int n = pair / heads;
  const int hd = pair - n * heads;
  const int beg = rowptr[n], end = rowptr[n + 1];
  const float sdv = s_dst[pair];

  // pass 1: segment max (wave-parallel over edges)
  float m = -3.402823466e38f;
  for (int i = beg + lane; i < end; i += 64) {
    float e = s_src[(size_t)cols[i] * heads + hd] + sdv;
    e = (e > 0.f) ? e : 0.2f * e;
    m = fmaxf(m, e);
  }
#pragma unroll
  for (int o = 32; o; o >>= 1) m = fmaxf(m, __shfl_xor(m, o));

  // pass 2: denom
  float dsum = 0.f;
  for (int i = beg + lane; i < end; i += 64) {
    float e = s_src[(size_t)cols[i] * heads + hd] + sdv;
    e = (e > 0.f) ? e : 0.2f * e;
    dsum += expf(e - m);
  }
#pragma unroll
  for (int o = 32; o; o >>= 1) dsum += __shfl_xor(dsum, o);
  const float rdsum = 1.f / (dsum + 1e-16f);

  // pass 3: weighted aggregation; lane owns channels {j*256 + lane*4 .. +3}, j=0..2
  float a[12];
#pragma unroll
  for (int q = 0; q < 12; ++q) a[q] = 0.f;
  const size_t hs = (size_t)heads * kH;
  const size_t hoff = (size_t)hd * kH + (size_t)lane * 4;
  for (int i = beg; i < end; ++i) {
    int src = cols[i];
    float e = s_src[(size_t)src * heads + hd] + sdv;
    e = (e > 0.f) ? e : 0.2f * e;
    float wgt = expf(e - m) * rdsum;
    const __hip_bfloat16* hp = h + (size_t)src * hs + hoff;
#pragma unroll
    for (int j = 0; j < 3; ++j) {
      uint2 v = *(const uint2*)(hp + j * 256);
      a[j * 4 + 0] = fmaf(wgt, blo(v.x), a[j * 4 + 0]);
      a[j * 4 + 1] = fmaf(wgt, bhi(v.x), a[j * 4 + 1]);
      a[j * 4 + 2] = fmaf(wgt, blo(v.y), a[j * 4 + 2]);
      a[j * 4 + 3] = fmaf(wgt, bhi(v.y), a[j * 4 + 3]);
    }
  }
  const size_t ob = (size_t)n * hs + hoff;
  const size_t bb = (size_t)hd * kH + (size_t)lane * 4;
#pragma unroll
  for (int j = 0; j < 3; ++j) {
#pragma unroll
    for (int q = 0; q < 4; ++q) {
      float v = a[j * 4 + q] + bias[bb + j * 256 + q];
      if (act) v = fmaxf(v, 0.f);
      if (out_bf) out_bf[ob + j * 256 + q] = __float2bfloat16(v);
      else out_f[ob + j * 256 + q] = v;
    }
  }
}

// ---------------- MLP head ----------------
__global__ void cat_kernel(const float* __restrict__ xf, const float* __restrict__ text_emb,
                           const float* __restrict__ img_emb, const int* __restrict__ user_idx,
                           const int* __restrict__ business_idx, __hip_bfloat16* __restrict__ cat) {
  int b = blockIdx.x;
  int u = user_idx[b], z = business_idx[b];
  __hip_bfloat16* crow = cat + (size_t)b * 4 * kH;
  for (int c = threadIdx.x; c < kH; c += blockDim.x) {
    crow[c] = __float2bfloat16(xf[(size_t)u * kH + c]);
    crow[kH + c] = __float2bfloat16(xf[(size_t)z * kH + c]);
    crow[2 * kH + c] = __float2bfloat16(text_emb[(size_t)b * kH + c]);
    crow[3 * kH + c] = __float2bfloat16(img_emb[(size_t)b * kH + c]);
  }
}

__global__ __launch_bounds__(256) void final_kernel(const float* __restrict__ m2,
                                                    const float* __restrict__ Wf3,
                                                    const float* __restrict__ bf3,
                                                    float* __restrict__ out) {
  int b = (blockIdx.x * 256 + threadIdx.x) >> 6;
  int lane = threadIdx.x & 63;
  if (b >= kB) return;
  float s = 0.f;
  for (int c = lane; c < kH; c += 64) s = fmaf(m2[(size_t)b * kH + c], Wf3[c], s);
#pragma unroll
  for (int o = 32; o; o >>= 1) s += __shfl_down(s, o);
  if (lane == 0) out[b] = s + bf3[0];
}

}  // namespace

extern "C" void kernel_launch(void* const* d_in, const int* in_sizes, int n_in,
                              void* d_out, int out_size, void* d_ws, size_t ws_size,
                              hipStream_t stream) {
  const float* text_cls = (const float*)d_in[0];
  const float* img_cls = (const float*)d_in[1];
  const float* biz_feats = (const float*)d_in[2];
  const float* W_text = (const float*)d_in[3];
  const float* b_text = (const float*)d_in[4];
  const float* W_img = (const float*)d_in[5];
  const float* b_img = (const float*)d_in[6];
  const float* W_bf = (const float*)d_in[7];
  const float* b_bf = (const float*)d_in[8];
  const float* user_table = (const float*)d_in[9];
  const float* biz_table = (const float*)d_in[10];
  const float* W1 = (const float*)d_in[11];
  const float* att_src1 = (const float*)d_in[12];
  const float* att_dst1 = (const float*)d_in[13];
  const float* b1 = (const float*)d_in[14];
  const float* W2 = (const float*)d_in[15];
  const float* att_src2 = (const float*)d_in[16];
  const float* att_dst2 = (const float*)d_in[17];
  const float* b2 = (const float*)d_in[18];
  const float* Wf1 = (const float*)d_in[19];
  const float* bf1 = (const float*)d_in[20];
  const float* Wf2 = (const float*)d_in[21];
  const float* bf2 = (const float*)d_in[22];
  const float* Wf3 = (const float*)d_in[23];
  const float* bf3 = (const float*)d_in[24];
  const int* user_idx = (const int*)d_in[25];
  const int* business_idx = (const int*)d_in[26];
  const int* edge_index = (const int*)d_in[27];
  float* out = (float*)d_out;
  (void)in_sizes; (void)n_in; (void)out_size; (void)ws_size;

  char* base = (char*)d_ws;
  size_t off = 0;
  auto alloc = [&](size_t bytes) -> void* {
    void* p = base + off;
    off = (off + bytes + 255) & ~(size_t)255;
    return p;
  };
  __hip_bfloat16* xb = (__hip_bfloat16*)alloc((size_t)kNN * kH * 2);
  __hip_bfloat16* text_bf = (__hip_bfloat16*)alloc((size_t)kB * kH * 2);
  __hip_bfloat16* imgm_bf = (__hip_bfloat16*)alloc((size_t)kB * kH * 2);
  float* text_emb = (float*)alloc((size_t)kB * kH * 4);
  float* img_emb = (float*)alloc((size_t)kB * kH * 4);
  __hip_bfloat16* Wtt = (__hip_bfloat16*)alloc((size_t)kH * kH * 2);
  __hip_bfloat16* Wit = (__hip_bfloat16*)alloc((size_t)kH * kH * 2);
  __hip_bfloat16* W1t = (__hip_bfloat16*)alloc((size_t)kHeads * kH * kH * 2);
  __hip_bfloat16* W2t = (__hip_bfloat16*)alloc((size_t)kH * kHeads * kH * 2);
  __hip_bfloat16* Wf1t = (__hip_bfloat16*)alloc((size_t)2 * kH * 4 * kH * 2);
  __hip_bfloat16* Wf2t = (__hip_bfloat16*)alloc((size_t)kH * 2 * kH * 2);
  __hip_bfloat16* h1 = (__hip_bfloat16*)alloc((size_t)kNN * kHeads * kH * 2);
  __hip_bfloat16* x2 = (__hip_bfloat16*)alloc((size_t)kNN * kHeads * kH * 2);
  __hip_bfloat16* h2 = (__hip_bfloat16*)alloc((size_t)kNN * kH * 2);
  float* xf = (float*)alloc((size_t)kNN * kH * 4);
  float* s1s = (float*)alloc((size_t)kNN * kHeads * 4);
  float* s1d = (float*)alloc((size_t)kNN * kHeads * 4);
  float* s2s = (float*)alloc((size_t)kNN * 4);
  float* s2d = (float*)alloc((size_t)kNN * 4);
  __hip_bfloat16* catb = (__hip_bfloat16*)alloc((size_t)kB * 4 * kH * 2);
  __hip_bfloat16* m1 = (__hip_bfloat16*)alloc((size_t)kB * 2 * kH * 2);
  float* m2 = (float*)alloc((size_t)kB * kH * 4);
  int* deg = (int*)alloc((size_t)kNN * 4);
  int* rowptr = (int*)alloc((size_t)(kNN + 1) * 4);
  int* cursor = (int*)alloc((size_t)kNN * 4);
  int* cols = (int*)alloc((size_t)kET * 4);
  int* winner = (int*)alloc((size_t)kNB * 4);

  // split-K partials aliased over h1 (dead after scores1/agg1): exact fit
  float* part = (float*)h1;

  hipMemsetAsync(xb, 0, (size_t)kNN * kH * 2, stream);
  hipMemsetAsync(deg, 0, (size_t)kNN * 4, stream);
  hipMemsetAsync(winner, 0xFF, (size_t)kNB * 4, stream);

  // batched weight transposes (f32 [K][N] -> bf16 [N][K]) — one launch
  TJobs tj;
  tj.in[0] = W_text; tj.out[0] = Wtt;  tj.K[0] = kH;          tj.N[0] = kH;
  tj.in[1] = W_img;  tj.out[1] = Wit;  tj.K[1] = kH;          tj.N[1] = kH;
  tj.in[2] = W1;     tj.out[2] = W1t;  tj.K[2] = kH;          tj.N[2] = kHeads * kH;
  tj.in[3] = W2;     tj.out[3] = W2t;  tj.K[3] = kHeads * kH; tj.N[3] = kH;
  tj.in[4] = Wf1;    tj.out[4] = Wf1t; tj.K[4] = 4 * kH;      tj.N[4] = 2 * kH;
  tj.in[5] = Wf2;    tj.out[5] = Wf2t; tj.K[5] = 2 * kH;      tj.N[5] = kH;
  tj.start[0] = 0;
  for (int q = 0; q < 6; ++q)
    tj.start[q + 1] = tj.start[q] + (tj.K[q] / 32) * (tj.N[q] / 32);
  transp_all_kernel<<<tj.start[6], 256, 0, stream>>>(tj);

  // input conversions (merged)
  prep_inputs_kernel<<<(kB * kH + 255) / 256, 256, 0, stream>>>(text_cls, img_cls, text_bf,
                                                                imgm_bf);

  // encoders, batched in z (grid 12x16x2 = 384 blocks)
  mfma_gemm_dual<64, 64, 2, 2><<<dim3(kH / 64, kB / 64, 2), 256, 0, stream>>>(
      text_bf, Wtt, b_text, text_emb, imgm_bf, Wit, b_img, img_emb, kB, kH, kH);

  // CSR degree + winner (merged)
  deg_winner_kernel<<<(kET + 255) / 256, 256, 0, stream>>>(edge_index, deg, business_idx, winner);
  scan_kernel<<<1, 1024, 0, stream>>>(deg, rowptr, cursor);
  fill_kernel<<<(kET + 255) / 256, 256, 0, stream>>>(edge_index, cursor, cols);

  // node features (merged users+businesses)
  build_x_kernel<<<kNN, 256, 0, stream>>>(user_idx, user_table, winner, text_emb, img_emb,
                                          biz_feats, W_bf, b_bf, biz_table, xb);

  // GAT layer 1 (8 heads): 48x24 = 1152 blocks, M-fast swizzle (A panel L2-resident)
  mfma_gemm<128, 128, 4, 4, __hip_bfloat16, true>
      <<<dim3(kHeads * kH / 128, kNN / 128), 256, 0, stream>>>(
          xb, W1t, nullptr, h1, kNN, kHeads * kH, kH, 0);
  scores_kernel<<<(kNN * kHeads + 3) / 4, 256, 0, stream>>>(h1, att_src1, att_dst1, s1s, s1d,
                                                            kNN * kHeads, kHeads);
  gat_agg_kernel<<<(kNN * kHeads) / 4, 256, 0, stream>>>(rowptr, cols, s1s, s1d, h1, b1, kHeads,
                                                         1, x2, nullptr, kNN * kHeads);

  // GAT layer 2 (1 head): split-K, BM=64 => 6x48x4 = 1152 blocks
  mfma_gemm_splitk<64, 128, 2, 4><<<dim3(kH / 128, kNN / 64, kSplitK), 256, 0, stream>>>(
      x2, W2t, part, kNN, kH, kHeads * kH, kHeads * kH / kSplitK);
  splitk_reduce_kernel<<<(kNN * kH / 4 + 255) / 256, 256, 0, stream>>>(
      part, h2, kNN * kH / 4, kSplitK);
  scores_kernel<<<(kNN + 3) / 4, 256, 0, stream>>>(h2, att_src2, att_dst2, s2s, s2d, kNN, 1);
  gat_agg_kernel<<<kNN / 4, 256, 0, stream>>>(rowptr, cols, s2s, s2d, h2, b2, 1, 0, nullptr, xf,
                                              kNN);

  // MLP head
  cat_kernel<<<kB, 256, 0, stream>>>(xf, text_emb, img_emb, user_idx, business_idx, catb);
  mfma_gemm<64, 64, 2, 2, __hip_bfloat16, true><<<dim3(2 * kH / 64, kB / 64), 256, 0, stream>>>(
      catb, Wf1t, bf1, m1, kB, 2 * kH, 4 * kH, 1);
  mfma_gemm<64, 64, 2, 2, float, true><<<dim3(kH / 64, kB / 64), 256, 0, stream>>>(
      m1, Wf2t, bf2, m2, kB, kH, 2 * kH, 1);
  final_kernel<<<(kB * 64 + 255) / 256, 256, 0, stream>>>(m2, Wf3, bf3, out);
}